// Round 6
// baseline (804.234 us; speedup 1.0000x reference)
//
#include <hip/hip_runtime.h>
#include <cstdint>

// B=8, Cin=Cout=128, x 128x128 -> out 256x256.
#define SCALE_MAIN 0.029462782549439483f   // 1/sqrt(128*9)
#define LSCALE     0.044194173824159223f   // 1/sqrt(512)
#define CSCALE     0.029462782549439483f   // 1/sqrt(128*9)

typedef __attribute__((ext_vector_type(8))) short bf16x8;
typedef __attribute__((ext_vector_type(4))) float f32x4;
typedef __attribute__((ext_vector_type(4))) unsigned int u32x4;

static __device__ __forceinline__ float lrelu_s2(float v) {
  return (v > 0.f ? v : 0.2f * v) * 1.4142135623730951f;
}
static __device__ __forceinline__ unsigned short f2bf(float f) {
  unsigned int u = __builtin_bit_cast(unsigned int, f);
  u += 0x7FFFu + ((u >> 16) & 1u);
  return (unsigned short)(u >> 16);
}
static __device__ __forceinline__ float s2f(unsigned short s) {
  return __builtin_bit_cast(float, (unsigned int)s << 16);
}

// ---------------------------------------------------------------------------
// K1 prep_all: [0,2048) kb2 | [2048,2624) kbu | [2624,3648) xpose | rest style
// kbu: unfused convT weights, bf16 B-layout [t9][s4][ksub4][co128][j8],
//      ci = s*32+ksub*8+j, tap t -> (plane, du, dv, wr, wc).
// ---------------------------------------------------------------------------
__global__ __launch_bounds__(256) void prep_all(
    const float* __restrict__ weight, const float* __restrict__ cw_w,
    const float* __restrict__ cb_w, const float* __restrict__ x,
    const float* __restrict__ style, const float* __restrict__ lin_w,
    const float* __restrict__ lin_b, short* __restrict__ kbu,
    short* __restrict__ kb2, unsigned short* __restrict__ xt,
    unsigned short* __restrict__ smap_bf) {
  int bid = blockIdx.x;
  int t = threadIdx.x;
  if (bid < 2048) {
    // ---- kb2: per-parity 2x2-tap modulation-conv weights (both convs) ----
    int idx = bid * 256 + t;
    int j   = idx & 7;
    int co  = (idx >> 3) & 255;
    int kc  = (idx >> 11) & 63;
    int par = idx >> 17;
    int k = kc * 8 + j;
    int t2 = k >> 7, ci = k & 127;
    int dy2 = t2 >> 1, dx2 = t2 & 1;
    int ph = par >> 1, pw = par & 1;
    const float* wsrc = (co < 128)
        ? cw_w + ((size_t)co * 128 + ci) * 9
        : cb_w + ((size_t)(co - 128) * 128 + ci) * 9;
    float acc = 0.f;
    #pragma unroll
    for (int kh = 0; kh < 3; ++kh) {
      bool okh = dy2 == 0 ? (ph == 0 ? kh == 0 : kh <= 1)
                          : (ph == 0 ? kh >= 1 : kh == 2);
      if (!okh) continue;
      #pragma unroll
      for (int kw = 0; kw < 3; ++kw) {
        bool okw = dx2 == 0 ? (pw == 0 ? kw == 0 : kw <= 1)
                            : (pw == 0 ? kw >= 1 : kw == 2);
        if (okw) acc += wsrc[kh * 3 + kw];
      }
    }
    kb2[idx] = (short)f2bf(acc * CSCALE);
  } else if (bid < 2624) {
    // ---- kbu: unfused convT taps ----
    int idx2 = (bid - 2048) * 256 + t;       // < 147456
    int j    = idx2 & 7;
    int co   = (idx2 >> 3) & 127;
    int ksub = (idx2 >> 10) & 3;
    int s    = (idx2 >> 12) & 3;
    int tp   = idx2 >> 14;                   // tap 0..8
    int ci = s * 32 + ksub * 8 + j;
    int wr = (tp == 0 || tp == 1 || tp == 4) ? 2
           : (tp >= 6) ? 1 : 0;
    int wc = (tp == 0 || tp == 2 || tp == 6) ? 2
           : (tp == 4 || tp == 5 || tp == 8) ? 1 : 0;
    float v = weight[((size_t)(co * 128 + ci)) * 9 + wr * 3 + wc] * SCALE_MAIN;
    kbu[idx2] = (short)f2bf(v);
  } else if (bid < 3648) {
    // ---- xpose: x NCHW fp32 -> NHWC bf16 ----
    int q = bid - 2624;
    int y = q & 127, b = q >> 7;
    __shared__ unsigned short tl[128 * 134];
    #pragma unroll 4
    for (int i = 0; i < 16; ++i) {
      int c = t + i * 256;
      int ci = c >> 5, x4 = c & 31;
      f32x4 v = *(const f32x4*)(x + (size_t)(b * 128 + ci) * 16384 + y * 128 + x4 * 4);
      unsigned int* dst = (unsigned int*)(tl + ci * 134 + x4 * 4);
      dst[0] = (unsigned int)f2bf(v.x) | ((unsigned int)f2bf(v.y) << 16);
      dst[1] = (unsigned int)f2bf(v.z) | ((unsigned int)f2bf(v.w) << 16);
    }
    __syncthreads();
    #pragma unroll 2
    for (int i = 0; i < 8; ++i) {
      int c = t + i * 256;
      int xcol = c >> 4, sub = c & 15;
      unsigned short u[8];
      #pragma unroll
      for (int j = 0; j < 8; ++j) u[j] = tl[(sub * 8 + j) * 134 + xcol];
      u32x4 o;
      o.x = (unsigned int)u[0] | ((unsigned int)u[1] << 16);
      o.y = (unsigned int)u[2] | ((unsigned int)u[3] << 16);
      o.z = (unsigned int)u[4] | ((unsigned int)u[5] << 16);
      o.w = (unsigned int)u[6] | ((unsigned int)u[7] << 16);
      *(u32x4*)(xt + ((size_t)(b * 128 + y) * 128 + xcol) * 128 + sub * 8) = o;
    }
  } else {
    // ---- style GEMV + fused lrelu -> smap_bf[b][sp(16x16)][ci] ----
    int wid = t >> 6, lane = t & 63;
    int gw = (bid - 3648) * 4 + wid;
    const float4* st4 = (const float4*)style;
    float s[8][8];
    #pragma unroll
    for (int b = 0; b < 8; ++b) {
      float4 a0 = st4[b * 128 + lane * 2];
      float4 a1 = st4[b * 128 + lane * 2 + 1];
      s[b][0] = a0.x; s[b][1] = a0.y; s[b][2] = a0.z; s[b][3] = a0.w;
      s[b][4] = a1.x; s[b][5] = a1.y; s[b][6] = a1.z; s[b][7] = a1.w;
    }
    for (int rr = 0; rr < 16; ++rr) {
      int j = gw * 16 + rr;
      const float4* wp = (const float4*)(lin_w + (size_t)j * 512);
      float4 w0 = wp[lane * 2], w1 = wp[lane * 2 + 1];
      float acc[8];
      #pragma unroll
      for (int b = 0; b < 8; ++b) {
        acc[b] = w0.x * s[b][0] + w0.y * s[b][1] + w0.z * s[b][2] + w0.w * s[b][3]
               + w1.x * s[b][4] + w1.y * s[b][5] + w1.z * s[b][6] + w1.w * s[b][7];
      }
      #pragma unroll
      for (int m = 32; m; m >>= 1) {
        #pragma unroll
        for (int b = 0; b < 8; ++b) acc[b] += __shfl_xor(acc[b], m, 64);
      }
      if (lane == 0) {
        float bias = lin_b[j];
        int ci = j >> 8, sp = j & 255;
        #pragma unroll
        for (int b = 0; b < 8; ++b)
          smap_bf[(size_t)(b * 256 + sp) * 128 + ci] =
              f2bf(lrelu_s2(acc[b] * LSCALE + bias));
      }
    }
  }
}

// ---------------------------------------------------------------------------
// K2 modconv: modulation convs as MFMA implicit GEMM (unchanged, verified).
// ---------------------------------------------------------------------------
__global__ __launch_bounds__(512, 2) void modconv_kernel(
    const unsigned short* __restrict__ smap_bf, const short* __restrict__ kb2,
    const float* __restrict__ cw_b, const float* __restrict__ cb_b,
    float* __restrict__ swp) {
  extern __shared__ __align__(16) char dsm[];   // 73984 B
  int par = blockIdx.x, b = blockIdx.y;
  int ph = par >> 1, pw = par & 1;
  int t = threadIdx.x, lane = t & 63, w = t >> 6;
  int q = w >> 1, ch = w & 1;
  int m15 = lane & 15, ksub = lane >> 4;

  for (int c = t; c < 4624; c += 512) {
    int s = c >> 4, cch = c & 15;
    int rr = s / 17, cc = s - rr * 17;
    int gr = rr - 1 + ph, gc = cc - 1 + pw;
    u32x4 v = {0u, 0u, 0u, 0u};
    if ((unsigned)gr < 16u && (unsigned)gc < 16u)
      v = *(const u32x4*)(smap_bf + ((size_t)(b * 256 + gr * 16 + gc) * 128 + cch * 8));
    int phys = (cch + s) & 15;
    *(u32x4*)(dsm + s * 256 + phys * 16) = v;
  }
  __syncthreads();

  const bf16x8* kbv = (const bf16x8*)kb2;
  f32x4 acc[4][8];
  #pragma unroll
  for (int i = 0; i < 4; ++i)
  #pragma unroll
  for (int j = 0; j < 8; ++j) acc[i][j] = (f32x4){0.f, 0.f, 0.f, 0.f};

  for (int s = 0; s < 16; ++s) {
    int t2 = s >> 2, dy2 = t2 >> 1, dx2 = t2 & 1;
    int cch = (s & 3) * 4 + ksub;
    bf16x8 av[4];
    #pragma unroll
    for (int mf = 0; mf < 4; ++mf) {
      int i = q * 4 + mf;
      int ssp = (i + dy2) * 17 + (m15 + dx2);
      int phys = (cch + ssp) & 15;
      av[mf] = *(const bf16x8*)(dsm + ssp * 256 + phys * 16);
    }
    #pragma unroll
    for (int nf = 0; nf < 8; ++nf) {
      bf16x8 bv = kbv[(size_t)((par * 64 + s * 4 + ksub) * 256 + ch * 128 + nf * 16 + m15)];
      #pragma unroll
      for (int mf = 0; mf < 4; ++mf)
        acc[mf][nf] = __builtin_amdgcn_mfma_f32_16x16x32_bf16(av[mf], bv, acc[mf][nf], 0, 0, 0);
    }
  }

  int jbase = ksub * 4;
  #pragma unroll
  for (int nf = 0; nf < 8; ++nf) {
    int co = ch * 128 + nf * 16 + m15;
    float bias = (co < 128) ? cw_b[co] : cb_b[co - 128];
    #pragma unroll
    for (int mf = 0; mf < 4; ++mf) {
      int i = q * 4 + mf;
      #pragma unroll
      for (int r = 0; r < 4; ++r) {
        int px = i * 16 + jbase + r;
        swp[((size_t)(b * 256 + co) * 4 + par) * 256 + px] = acc[mf][nf][r] + bias;
      }
    }
  }
}

// ---------------------------------------------------------------------------
// K3 convt: unfused transposed conv -> 4 parity planes, bf16.
// plane(0,0)[r,c]=x[r-1,c-1]w22+x[r-1,c]w20+x[r,c-1]w02+x[r,c]w00
// plane(0,1)[r,c]=x[r-1,c]w21+x[r,c]w01 ; plane(1,0)=x[r,c-1]w12+x[r,c]w10
// plane(1,1)[r,c]=x[r,c]w11.  (w = SCALE_MAIN*weight)
// Block: 576 thr = 9 waves, one TAP per wave (K=128 each, balanced).
// All waves share one 64-px tile (2 plane-rows x 32 cols). Cross-wave tap
// sums via eps LDS. Edges (r=128/c=128) come free from zero-masked staging.
// out1 layout: [b][pl][co][r:130][c stride 132] bf16.
// ---------------------------------------------------------------------------
__global__ __launch_bounds__(576) void convt_kernel(
    const unsigned short* __restrict__ xt, const short* __restrict__ kbu,
    unsigned short* __restrict__ out1) {
  extern __shared__ __align__(16) char dsm2[];     // 26928 A-tile + 39168 eps
  char* smem = dsm2;
  float* eps = (float*)(dsm2 + 26928);
  int cg = blockIdx.x, rp = blockIdx.y, b = blockIdx.z;
  int r0 = rp * 2, c0 = cg * 32;
  int t = threadIdx.x, lane = t & 63, w = t >> 6;  // w = tap 0..8
  int m15 = lane & 15, ksub = lane >> 4;

  // ---- stage A tile: 3 rows x 33 cols x 128 ci bf16, zero-masked ----
  const char* xtc = (const char*)xt;
  for (int c = t; c < 1584; c += 576) {
    int spos = c >> 4, sub = c & 15;
    int lr = spos / 33, lc = spos - lr * 33;
    int y = r0 - 1 + lr, xg = c0 - 1 + lc;
    f32x4 v = {0.f, 0.f, 0.f, 0.f};
    if ((unsigned)y < 128u && (unsigned)xg < 128u)
      v = *(const f32x4*)(xtc + ((size_t)((b * 128 + y) * 128 + xg)) * 256 + sub * 16);
    *(f32x4*)(smem + spos * 272 + sub * 16) = v;
  }
  __syncthreads();

  int du = (w == 0 || w == 1 || w == 4) ? -1 : 0;
  int dv = (w == 0 || w == 2 || w == 6) ? -1 : 0;
  const char* abase[4];
  #pragma unroll
  for (int mf = 0; mf < 4; ++mf)
    abase[mf] = smem + (((mf >> 1) + du + 1) * 33 + (mf & 1) * 16 + m15 + dv + 1) * 272
              + ksub * 16;
  const bf16x8* kbv = (const bf16x8*)kbu;
  int bb = w * 2048 + ksub * 128 + m15;

  f32x4 acc[4][8];
  #pragma unroll
  for (int i = 0; i < 4; ++i)
  #pragma unroll
  for (int j = 0; j < 8; ++j) acc[i][j] = (f32x4){0.f, 0.f, 0.f, 0.f};

  auto LD = [&](int s, bf16x8* av, bf16x8* bv) {
    #pragma unroll
    for (int mf = 0; mf < 4; ++mf) av[mf] = *(const bf16x8*)(abase[mf] + s * 64);
    #pragma unroll
    for (int nf = 0; nf < 8; ++nf) bv[nf] = kbv[bb + s * 512 + nf * 16];
  };
  auto MM = [&](bf16x8* av, bf16x8* bv) {
    #pragma unroll
    for (int nf = 0; nf < 8; ++nf)
    #pragma unroll
    for (int mf = 0; mf < 4; ++mf)
      acc[mf][nf] = __builtin_amdgcn_mfma_f32_16x16x32_bf16(av[mf], bv[nf], acc[mf][nf], 0, 0, 0);
  };
  bf16x8 aA[4], bA[8], aB[4], bB[8];
  LD(0, aA, bA); LD(1, aB, bB);
  MM(aA, bA);    LD(2, aA, bA);
  MM(aB, bB);    LD(3, aB, bB);
  MM(aA, bA);    MM(aB, bB);

  __syncthreads();
  // ---- epilogue: 8 nf rounds; tap-sum via eps; bf16 plane writes ----
  for (int nf = 0; nf < 8; ++nf) {
    #pragma unroll
    for (int mf = 0; mf < 4; ++mf)
    #pragma unroll
    for (int r = 0; r < 4; ++r)
      eps[(w * 64 + mf * 16 + ksub * 4 + r) * 17 + m15] = acc[mf][nf][r];
    __syncthreads();
    for (int idx = t; idx < 4096; idx += 576) {
      int c5 = idx & 31, co16 = (idx >> 5) & 15;
      int prow = (idx >> 9) & 1, pl = idx >> 10;
      int px = prow * 32 + c5;
      int start = (pl == 0) ? 0 : (pl == 1) ? 4 : (pl == 2) ? 6 : 8;
      int cnt   = (pl == 0) ? 4 : (pl == 3) ? 1 : 2;
      float v = 0.f;
      for (int k = 0; k < cnt; ++k)
        v += eps[((start + k) * 64 + px) * 17 + co16];
      int r = r0 + prow, cc = c0 + c5, co = nf * 16 + co16;
      if (cc < 129)
        out1[((((size_t)(b * 4 + pl) * 128 + co) * 130 + r) * 132 + cc)] = f2bf(v);
    }
    __syncthreads();
  }
}

// ---------------------------------------------------------------------------
// K4/K5 blur: separable [1,3,3,1]^2 /16 over parity planes.
// PASS 0: stats partials per (b,co,64x64 strip). PASS 1: recompute blur,
// normalize + modulate + write fp32 d_out (stats reduced inline from part).
// ---------------------------------------------------------------------------
template <int PASS>
__global__ __launch_bounds__(256) void blur_kernel(
    const unsigned short* __restrict__ out1, float* __restrict__ part,
    const float* __restrict__ swp, float* __restrict__ dout) {
  __shared__ unsigned short S[4][34][36];
  __shared__ float T[64 * 2 * 34];
  __shared__ float msh[2];
  __shared__ float rb2[8];
  int bx = blockIdx.x;
  int tt = bx & 3, ss = bx >> 2;
  int co = blockIdx.y, b = blockIdx.z;
  int t = threadIdx.x, lane = t & 63, wid = t >> 6;
  int bc = b * 128 + co;

  if (PASS == 1 && t == 0) {
    float s1 = 0.f, s2 = 0.f;
    #pragma unroll
    for (int i = 0; i < 16; ++i) {
      s1 += part[((size_t)bc * 16 + i) * 2];
      s2 += part[((size_t)bc * 16 + i) * 2 + 1];
    }
    float mean = s1 * (1.f / 65536.f);
    float var = s2 * (1.f / 65536.f) - mean * mean;
    msh[0] = mean; msh[1] = rsqrtf(var + 1e-5f);
  }

  // ---- stage 4 planes: rows 32ss-1..32ss+32, cols 32tt-2..32tt+33 ----
  int rb = 32 * ss - 1, cb = 32 * tt - 2;
  for (int i = t; i < 2448; i += 256) {         // 4*34*18 u32 pairs
    int pl = i / 612, rem = i - pl * 612;
    int lr = rem / 18, cp = rem - lr * 18;
    int r = rb + lr, c = cb + cp * 2;
    int Rp = (pl < 2) ? 129 : 128;
    int Cp = (pl & 1) ? 128 : 129;
    const unsigned short* base = out1 + (((size_t)(b * 4 + pl) * 128 + co) * 130 + r) * 132;
    unsigned int v = 0u;
    if ((unsigned)r < (unsigned)Rp) {
      if (c >= 0 && c + 1 < Cp) v = *(const unsigned int*)(base + c);
      else {
        unsigned int lo = ((unsigned)c < (unsigned)Cp) ? base[c] : 0u;
        unsigned int hi = ((unsigned)(c + 1) < (unsigned)Cp) ? base[c + 1] : 0u;
        v = lo | (hi << 16);
      }
    }
    *(unsigned int*)(&S[pl][lr][cp * 2]) = v;
  }
  __syncthreads();

  // ---- vertical pass: T[hl][pw][cl], cl = plane-col - (32tt-1) ----
  for (int i = t; i < 4352; i += 256) {
    int hl = i / 68, rem = i - hl * 68;
    int pw = rem / 34, cl = rem - pw * 34;
    int lrb = (hl + 1) >> 1;
    int E = pw, O = 2 + pw;
    float v;
    if (hl & 1)
      v = s2f(S[E][lrb][cl + 1]) + 3.f * s2f(S[O][lrb][cl + 1])
        + 3.f * s2f(S[E][lrb + 1][cl + 1]) + s2f(S[O][lrb + 1][cl + 1]);
    else
      v = s2f(S[O][lrb][cl + 1]) + 3.f * s2f(S[E][lrb + 1][cl + 1])
        + 3.f * s2f(S[O][lrb + 1][cl + 1]) + s2f(S[E][lrb + 2][cl + 1]);
    T[(hl * 2 + pw) * 34 + cl] = v;
  }
  __syncthreads();

  float mean = 0.f, rstd = 0.f;
  if (PASS == 1) { mean = msh[0]; rstd = msh[1]; }
  float s1 = 0.f, s2 = 0.f;
  for (int i = t; i < 4096; i += 256) {
    int hl = i >> 6, wl = i & 63;
    int lcb = (wl + 1) >> 1;
    const float* T0 = &T[hl * 68];
    const float* T1 = T0 + 34;
    float v;
    if (wl & 1) v = T0[lcb] + 3.f * T1[lcb] + 3.f * T0[lcb + 1] + T1[lcb + 1];
    else        v = T1[lcb] + 3.f * T0[lcb + 1] + 3.f * T1[lcb + 1] + T0[lcb + 2];
    v *= 0.0625f;
    if (PASS == 0) {
      s1 += v; s2 += v * v;
    } else {
      int h = 64 * ss + hl, wg = 64 * tt + wl;
      int par = ((h >> 3) & 1) * 2 + ((wg >> 3) & 1);
      int px2 = (h >> 4) * 16 + (wg >> 4);
      float msw = swp[((size_t)(b * 256 + co) * 4 + par) * 256 + px2];
      float msb = swp[((size_t)(b * 256 + 128 + co) * 4 + par) * 256 + px2];
      float f1 = (1.f + 0.3f * msw) * rstd;
      float f0 = 0.3f * msb - mean * f1;
      dout[((size_t)bc * 256 + h) * 256 + wg] = v * f1 + f0;
    }
  }
  if (PASS == 0) {
    #pragma unroll
    for (int m = 32; m; m >>= 1) { s1 += __shfl_xor(s1, m, 64); s2 += __shfl_xor(s2, m, 64); }
    if (lane == 0) { rb2[wid * 2] = s1; rb2[wid * 2 + 1] = s2; }
    __syncthreads();
    if (t == 0) {
      part[((size_t)bc * 16 + bx) * 2]     = rb2[0] + rb2[2] + rb2[4] + rb2[6];
      part[((size_t)bc * 16 + bx) * 2 + 1] = rb2[1] + rb2[3] + rb2[5] + rb2[7];
    }
  }
}

extern "C" void kernel_launch(void* const* d_in, const int* in_sizes, int n_in,
                              void* d_out, int out_size, void* d_ws, size_t ws_size,
                              hipStream_t stream) {
  const float* x      = (const float*)d_in[0];
  const float* style  = (const float*)d_in[1];
  const float* weight = (const float*)d_in[2];
  const float* lin_w  = (const float*)d_in[3];
  const float* lin_b  = (const float*)d_in[4];
  const float* cw_w   = (const float*)d_in[5];
  const float* cw_b   = (const float*)d_in[6];
  const float* cb_w   = (const float*)d_in[7];
  const float* cb_b   = (const float*)d_in[8];
  float* out = (float*)d_out;
  char* ws = (char*)d_ws;

  short*          kbu     = (short*)(ws);                     //   294,912
  short*          kb2     = (short*)(ws + 294912);            // 1,048,576
  unsigned short* xt      = (unsigned short*)(ws + 1343488);  // 33,554,432
  unsigned short* smap_bf = (unsigned short*)(ws + 34897920); //   524,288
  float*          swp     = (float*)(ws + 35422208);          // 8,388,608
  float*          part    = (float*)(ws + 43810816);          //   131,072
  unsigned short* out1    = (unsigned short*)(ws + 43941888); // 140,574,720 (end 184.5MB)

  prep_all<<<dim3(4160), dim3(256), 0, stream>>>(
      weight, cw_w, cb_w, x, style, lin_w, lin_b, kbu, kb2, xt, smap_bf);
  modconv_kernel<<<dim3(4, 8), dim3(512), 73984, stream>>>(smap_bf, kb2, cw_b, cb_b, swp);
  convt_kernel<<<dim3(5, 65, 8), dim3(576), 66096, stream>>>(xt, kbu, out1);
  blur_kernel<0><<<dim3(16, 128, 8), dim3(256), 0, stream>>>(out1, part, swp, out);
  blur_kernel<1><<<dim3(16, 128, 8), dim3(256), 0, stream>>>(out1, part, swp, out);
}

// Round 7
// 518.443 us; speedup vs baseline: 1.5512x; 1.5512x over previous
//
#include <hip/hip_runtime.h>
#include <cstdint>

// B=8, Cin=Cout=128, x 128x128 -> out 256x256.
#define SCALE_MAIN 0.029462782549439483f   // 1/sqrt(128*9)
#define LSCALE     0.044194173824159223f   // 1/sqrt(512)
#define CSCALE     0.029462782549439483f   // 1/sqrt(128*9)

typedef __attribute__((ext_vector_type(8))) short bf16x8;
typedef __attribute__((ext_vector_type(4))) float f32x4;
typedef __attribute__((ext_vector_type(2))) unsigned int u32x2;
typedef __attribute__((ext_vector_type(4))) unsigned int u32x4;

static __device__ __forceinline__ float lrelu_s2(float v) {
  return (v > 0.f ? v : 0.2f * v) * 1.4142135623730951f;
}
static __device__ __forceinline__ unsigned short f2bf(float f) {
  unsigned int u = __builtin_bit_cast(unsigned int, f);
  u += 0x7FFFu + ((u >> 16) & 1u);
  return (unsigned short)(u >> 16);
}
static __device__ __forceinline__ float s2f(unsigned short s) {
  return __builtin_bit_cast(float, (unsigned int)s << 16);
}

// ---------------------------------------------------------------------------
// K1 prep_all: [0,2048) kb2 | [2048,2624) kbu | [2624,3648) xpose | rest style
// (verbatim from round 6 -- verified)
// ---------------------------------------------------------------------------
__global__ __launch_bounds__(256) void prep_all(
    const float* __restrict__ weight, const float* __restrict__ cw_w,
    const float* __restrict__ cb_w, const float* __restrict__ x,
    const float* __restrict__ style, const float* __restrict__ lin_w,
    const float* __restrict__ lin_b, short* __restrict__ kbu,
    short* __restrict__ kb2, unsigned short* __restrict__ xt,
    unsigned short* __restrict__ smap_bf) {
  int bid = blockIdx.x;
  int t = threadIdx.x;
  if (bid < 2048) {
    int idx = bid * 256 + t;
    int j   = idx & 7;
    int co  = (idx >> 3) & 255;
    int kc  = (idx >> 11) & 63;
    int par = idx >> 17;
    int k = kc * 8 + j;
    int t2 = k >> 7, ci = k & 127;
    int dy2 = t2 >> 1, dx2 = t2 & 1;
    int ph = par >> 1, pw = par & 1;
    const float* wsrc = (co < 128)
        ? cw_w + ((size_t)co * 128 + ci) * 9
        : cb_w + ((size_t)(co - 128) * 128 + ci) * 9;
    float acc = 0.f;
    #pragma unroll
    for (int kh = 0; kh < 3; ++kh) {
      bool okh = dy2 == 0 ? (ph == 0 ? kh == 0 : kh <= 1)
                          : (ph == 0 ? kh >= 1 : kh == 2);
      if (!okh) continue;
      #pragma unroll
      for (int kw = 0; kw < 3; ++kw) {
        bool okw = dx2 == 0 ? (pw == 0 ? kw == 0 : kw <= 1)
                            : (pw == 0 ? kw >= 1 : kw == 2);
        if (okw) acc += wsrc[kh * 3 + kw];
      }
    }
    kb2[idx] = (short)f2bf(acc * CSCALE);
  } else if (bid < 2624) {
    int idx2 = (bid - 2048) * 256 + t;       // < 147456
    int j    = idx2 & 7;
    int co   = (idx2 >> 3) & 127;
    int ksub = (idx2 >> 10) & 3;
    int s    = (idx2 >> 12) & 3;
    int tp   = idx2 >> 14;                   // tap 0..8
    int ci = s * 32 + ksub * 8 + j;
    int wr = (tp == 0 || tp == 1 || tp == 4) ? 2
           : (tp >= 6) ? 1 : 0;
    int wc = (tp == 0 || tp == 2 || tp == 6) ? 2
           : (tp == 4 || tp == 5 || tp == 8) ? 1 : 0;
    float v = weight[((size_t)(co * 128 + ci)) * 9 + wr * 3 + wc] * SCALE_MAIN;
    kbu[idx2] = (short)f2bf(v);
  } else if (bid < 3648) {
    int q = bid - 2624;
    int y = q & 127, b = q >> 7;
    __shared__ unsigned short tl[128 * 134];
    #pragma unroll 4
    for (int i = 0; i < 16; ++i) {
      int c = t + i * 256;
      int ci = c >> 5, x4 = c & 31;
      f32x4 v = *(const f32x4*)(x + (size_t)(b * 128 + ci) * 16384 + y * 128 + x4 * 4);
      unsigned int* dst = (unsigned int*)(tl + ci * 134 + x4 * 4);
      dst[0] = (unsigned int)f2bf(v.x) | ((unsigned int)f2bf(v.y) << 16);
      dst[1] = (unsigned int)f2bf(v.z) | ((unsigned int)f2bf(v.w) << 16);
    }
    __syncthreads();
    #pragma unroll 2
    for (int i = 0; i < 8; ++i) {
      int c = t + i * 256;
      int xcol = c >> 4, sub = c & 15;
      unsigned short u[8];
      #pragma unroll
      for (int j = 0; j < 8; ++j) u[j] = tl[(sub * 8 + j) * 134 + xcol];
      u32x4 o;
      o.x = (unsigned int)u[0] | ((unsigned int)u[1] << 16);
      o.y = (unsigned int)u[2] | ((unsigned int)u[3] << 16);
      o.z = (unsigned int)u[4] | ((unsigned int)u[5] << 16);
      o.w = (unsigned int)u[6] | ((unsigned int)u[7] << 16);
      *(u32x4*)(xt + ((size_t)(b * 128 + y) * 128 + xcol) * 128 + sub * 8) = o;
    }
  } else {
    int wid = t >> 6, lane = t & 63;
    int gw = (bid - 3648) * 4 + wid;
    const float4* st4 = (const float4*)style;
    float s[8][8];
    #pragma unroll
    for (int b = 0; b < 8; ++b) {
      float4 a0 = st4[b * 128 + lane * 2];
      float4 a1 = st4[b * 128 + lane * 2 + 1];
      s[b][0] = a0.x; s[b][1] = a0.y; s[b][2] = a0.z; s[b][3] = a0.w;
      s[b][4] = a1.x; s[b][5] = a1.y; s[b][6] = a1.z; s[b][7] = a1.w;
    }
    for (int rr = 0; rr < 16; ++rr) {
      int j = gw * 16 + rr;
      const float4* wp = (const float4*)(lin_w + (size_t)j * 512);
      float4 w0 = wp[lane * 2], w1 = wp[lane * 2 + 1];
      float acc[8];
      #pragma unroll
      for (int b = 0; b < 8; ++b) {
        acc[b] = w0.x * s[b][0] + w0.y * s[b][1] + w0.z * s[b][2] + w0.w * s[b][3]
               + w1.x * s[b][4] + w1.y * s[b][5] + w1.z * s[b][6] + w1.w * s[b][7];
      }
      #pragma unroll
      for (int m = 32; m; m >>= 1) {
        #pragma unroll
        for (int b = 0; b < 8; ++b) acc[b] += __shfl_xor(acc[b], m, 64);
      }
      if (lane == 0) {
        float bias = lin_b[j];
        int ci = j >> 8, sp = j & 255;
        #pragma unroll
        for (int b = 0; b < 8; ++b)
          smap_bf[(size_t)(b * 256 + sp) * 128 + ci] =
              f2bf(lrelu_s2(acc[b] * LSCALE + bias));
      }
    }
  }
}

// ---------------------------------------------------------------------------
// K2 modconv (verbatim from round 5/6 -- verified)
// ---------------------------------------------------------------------------
__global__ __launch_bounds__(512, 2) void modconv_kernel(
    const unsigned short* __restrict__ smap_bf, const short* __restrict__ kb2,
    const float* __restrict__ cw_b, const float* __restrict__ cb_b,
    float* __restrict__ swp) {
  extern __shared__ __align__(16) char dsm[];   // 73984 B
  int par = blockIdx.x, b = blockIdx.y;
  int ph = par >> 1, pw = par & 1;
  int t = threadIdx.x, lane = t & 63, w = t >> 6;
  int q = w >> 1, ch = w & 1;
  int m15 = lane & 15, ksub = lane >> 4;

  for (int c = t; c < 4624; c += 512) {
    int s = c >> 4, cch = c & 15;
    int rr = s / 17, cc = s - rr * 17;
    int gr = rr - 1 + ph, gc = cc - 1 + pw;
    u32x4 v = {0u, 0u, 0u, 0u};
    if ((unsigned)gr < 16u && (unsigned)gc < 16u)
      v = *(const u32x4*)(smap_bf + ((size_t)(b * 256 + gr * 16 + gc) * 128 + cch * 8));
    int phys = (cch + s) & 15;
    *(u32x4*)(dsm + s * 256 + phys * 16) = v;
  }
  __syncthreads();

  const bf16x8* kbv = (const bf16x8*)kb2;
  f32x4 acc[4][8];
  #pragma unroll
  for (int i = 0; i < 4; ++i)
  #pragma unroll
  for (int j = 0; j < 8; ++j) acc[i][j] = (f32x4){0.f, 0.f, 0.f, 0.f};

  for (int s = 0; s < 16; ++s) {
    int t2 = s >> 2, dy2 = t2 >> 1, dx2 = t2 & 1;
    int cch = (s & 3) * 4 + ksub;
    bf16x8 av[4];
    #pragma unroll
    for (int mf = 0; mf < 4; ++mf) {
      int i = q * 4 + mf;
      int ssp = (i + dy2) * 17 + (m15 + dx2);
      int phys = (cch + ssp) & 15;
      av[mf] = *(const bf16x8*)(dsm + ssp * 256 + phys * 16);
    }
    #pragma unroll
    for (int nf = 0; nf < 8; ++nf) {
      bf16x8 bv = kbv[(size_t)((par * 64 + s * 4 + ksub) * 256 + ch * 128 + nf * 16 + m15)];
      #pragma unroll
      for (int mf = 0; mf < 4; ++mf)
        acc[mf][nf] = __builtin_amdgcn_mfma_f32_16x16x32_bf16(av[mf], bv, acc[mf][nf], 0, 0, 0);
    }
  }

  int jbase = ksub * 4;
  #pragma unroll
  for (int nf = 0; nf < 8; ++nf) {
    int co = ch * 128 + nf * 16 + m15;
    float bias = (co < 128) ? cw_b[co] : cb_b[co - 128];
    #pragma unroll
    for (int mf = 0; mf < 4; ++mf) {
      int i = q * 4 + mf;
      #pragma unroll
      for (int r = 0; r < 4; ++r) {
        int px = i * 16 + jbase + r;
        swp[((size_t)(b * 256 + co) * 4 + par) * 256 + px] = acc[mf][nf][r] + bias;
      }
    }
  }
}

// ---------------------------------------------------------------------------
// K3 convt v2: unfused transposed conv -> 4 parity planes, bf16.
// Block (cg,rp,b): tile = 2 plane rows (2rp,2rp+1) x 32 cols [32cg..+32) x
// 128 co. 4 waves, wave = one PLANE (rotated across SIMDs by block index):
//   pl00: taps 0-3 (K=512), pl01: 4-5, pl10: 6-7, pl11: 8.
// A-tile 3x34x128ci bf16, stride 256 + XOR chunk swizzle (conflict-free b128).
// Grid cols cover [0,160) masked to <132: col 128 real, 129-131 zero padding
// (x staged as 0 beyond bounds). Rows 0..129 likewise (128/129 real-or-zero).
// out1 layout: [b][pl][co][130 rows][132 cols] bf16.
// ---------------------------------------------------------------------------
__global__ __launch_bounds__(256, 2) void convt_kernel(
    const unsigned short* __restrict__ xt, const short* __restrict__ kbu,
    unsigned short* __restrict__ out1) {
  __shared__ __align__(16) char smem[26112];   // A-tile 102*256; reused as eps
  int cg = blockIdx.x, rp = blockIdx.y, b = blockIdx.z;
  int t = threadIdx.x, lane = t & 63, w = t >> 6;
  int m15 = lane & 15, ksub = lane >> 4;
  int pl = (w + cg + rp) & 3;                  // wave's plane, SIMD-balanced
  int tstart = (pl == 0) ? 0 : 2 + 2 * pl;     // {0,4,6,8}
  int nst = 16 >> ((pl + 1) >> 1);             // {16,8,8,4}

  // ---- stage A: 3 x-rows x 34 cols x 128 ci, XOR-swizzled chunks ----
  const char* xtc = (const char*)xt;
  for (int c = t; c < 1632; c += 256) {
    int spos = c >> 4, sub = c & 15;
    int lr = spos / 34, lc = spos - lr * 34;
    int y = 2 * rp - 1 + lr, xg = 32 * cg - 1 + lc;
    f32x4 v = {0.f, 0.f, 0.f, 0.f};
    if ((unsigned)y < 128u && (unsigned)xg < 128u)
      v = *(const f32x4*)(xtc + ((size_t)((b * 128 + y) * 128 + xg)) * 256 + sub * 16);
    int phys = (sub & 8) | ((sub ^ spos) & 7);
    *(f32x4*)(smem + spos * 256 + phys * 16) = v;
  }
  __syncthreads();

  const bf16x8* kbv = (const bf16x8*)kbu;
  f32x4 acc[4][8];
  #pragma unroll
  for (int i = 0; i < 4; ++i)
  #pragma unroll
  for (int j = 0; j < 8; ++j) acc[i][j] = (f32x4){0.f, 0.f, 0.f, 0.f};

  auto LD = [&](int s, bf16x8* av, bf16x8* bv) {
    int tap = tstart + (s >> 2);
    int du = -((0x13 >> tap) & 1);             // taps {0,1,4} have du=-1
    int dv = -((0x45 >> tap) & 1);             // taps {0,2,6} have dv=-1
    int cc = s & 3;
    int c = cc * 4 + ksub;
    #pragma unroll
    for (int mf = 0; mf < 4; ++mf) {
      int spos = ((mf >> 1) + du + 1) * 34 + (mf & 1) * 16 + m15 + dv + 1;
      int phys = (c & 8) | ((c ^ spos) & 7);
      av[mf] = *(const bf16x8*)(smem + spos * 256 + phys * 16);
    }
    int bb = tap * 2048 + cc * 512 + ksub * 128 + m15;
    #pragma unroll
    for (int nf = 0; nf < 8; ++nf) bv[nf] = kbv[bb + nf * 16];
  };
  auto MM = [&](bf16x8* av, bf16x8* bv) {
    __builtin_amdgcn_s_setprio(1);
    #pragma unroll
    for (int nf = 0; nf < 8; ++nf)
    #pragma unroll
    for (int mf = 0; mf < 4; ++mf)
      acc[mf][nf] = __builtin_amdgcn_mfma_f32_16x16x32_bf16(av[mf], bv[nf], acc[mf][nf], 0, 0, 0);
    __builtin_amdgcn_s_setprio(0);
  };

  bf16x8 aA[4], bA[8], aB[4], bB[8];
  LD(0, aA, bA);
  for (int s = 0; s + 2 <= nst; s += 2) {
    LD(s + 1, aB, bB);
    MM(aA, bA);
    if (s + 2 < nst) LD(s + 2, aA, bA);
    MM(aB, bB);
  }

  __syncthreads();
  // ---- epilogue: 8 nf rounds, fully unrolled (static acc indexing) ----
  float* eps = (float*)smem;                   // [pl 4][px 64][17]
  int t63 = t & 63, wpl = t >> 6;
  #pragma unroll
  for (int nf = 0; nf < 8; ++nf) {
    #pragma unroll
    for (int mf = 0; mf < 4; ++mf)
    #pragma unroll
    for (int r = 0; r < 4; ++r)
      eps[(pl * 64 + mf * 16 + ksub * 4 + r) * 17 + m15] = acc[mf][nf][r];
    __syncthreads();
    #pragma unroll
    for (int k = 0; k < 4; ++k) {
      int slot = k * 64 + t63;                 // [co16:4][pr:1][ch:3]
      int co16 = slot >> 4, pr = (slot >> 3) & 1, ch = slot & 7;
      float v0 = eps[(wpl * 64 + pr * 32 + ch * 4 + 0) * 17 + co16];
      float v1 = eps[(wpl * 64 + pr * 32 + ch * 4 + 1) * 17 + co16];
      float v2 = eps[(wpl * 64 + pr * 32 + ch * 4 + 2) * 17 + co16];
      float v3 = eps[(wpl * 64 + pr * 32 + ch * 4 + 3) * 17 + co16];
      u32x2 o;
      o.x = (unsigned int)f2bf(v0) | ((unsigned int)f2bf(v1) << 16);
      o.y = (unsigned int)f2bf(v2) | ((unsigned int)f2bf(v3) << 16);
      int co = nf * 16 + co16;
      int r = 2 * rp + pr;
      size_t ob = (((size_t)(b * 4 + wpl) * 128 + co) * 130 + r) * 132
                + 32 * cg + ch * 4;
      if (cg < 4 || ch == 0) *(u32x2*)(out1 + ob) = o;
    }
    __syncthreads();
  }
}

// ---------------------------------------------------------------------------
// K4/K5 blur v2: separable [1,3,3,1]^2/16 over parity planes, full-width
// strips. Block (g,co,b): out rows [32g,32g+32) x all 256 cols.
// PASS 0: stats partials -> part[bc][8][2]. PASS 1: normalize+modulate+write.
// ---------------------------------------------------------------------------
template <int PASS>
__global__ __launch_bounds__(256) void blur_kernel(
    const unsigned short* __restrict__ out1, float* __restrict__ part,
    const float* __restrict__ swp, float* __restrict__ dout) {
  __shared__ unsigned short S[4 * 18 * 132];   // 19008 B
  __shared__ float T[32 * 2 * 132];            // 33792 B
  __shared__ float msh[2];
  __shared__ float rb2[8];
  int g = blockIdx.x, co = blockIdx.y, b = blockIdx.z;
  int t = threadIdx.x, lane = t & 63, wid = t >> 6;
  int bc = b * 128 + co;

  if (PASS == 1 && t == 0) {
    float a1 = 0.f, a2 = 0.f;
    #pragma unroll
    for (int i = 0; i < 8; ++i) {
      a1 += part[((size_t)bc * 8 + i) * 2];
      a2 += part[((size_t)bc * 8 + i) * 2 + 1];
    }
    float mean = a1 * (1.f / 65536.f);
    float var = a2 * (1.f / 65536.f) - mean * mean;
    msh[0] = mean; msh[1] = rsqrtf(var + 1e-5f);
  }

  // ---- stage: 4 planes x 18 rows [16g-1..16g+16] x 132 cols (8B loads) ----
  int rb = 16 * g - 1;
  for (int i = t; i < 2376; i += 256) {
    int pl = i / 594; int rem = i - pl * 594;
    int lr = rem / 33; int lc8 = rem - lr * 33;
    int r = rb + lr;
    u32x2 v = {0u, 0u};
    if (r >= 0)
      v = *(const u32x2*)(out1 + ((size_t)((b * 4 + pl) * 128 + co) * 130 + r) * 132 + lc8 * 4);
    *(u32x2*)(&S[(pl * 18 + lr) * 132 + lc8 * 4]) = v;
  }
  if (t < 64) T[t * 132] = 0.f;                // cl=0 -> plane col -1 = 0
  __syncthreads();

  // ---- vertical: T[hl][pw][cl], cl = pc+1 in [1,130] ----
  for (int vi = t; vi < 8320; vi += 256) {
    int hl = vi / 260; int rem = vi - hl * 260;
    int pw = rem / 130; int cl = rem - pw * 130 + 1;
    int pc = cl - 1;
    int lrb = (hl + 1) >> 1;
    const unsigned short* E = &S[(pw * 18) * 132 + pc];
    const unsigned short* O = &S[((2 + pw) * 18) * 132 + pc];
    float v;
    if (hl & 1)
      v = s2f(E[lrb * 132]) + 3.f * s2f(O[lrb * 132])
        + 3.f * s2f(E[(lrb + 1) * 132]) + s2f(O[(lrb + 1) * 132]);
    else
      v = s2f(O[lrb * 132]) + 3.f * s2f(E[(lrb + 1) * 132])
        + 3.f * s2f(O[(lrb + 1) * 132]) + s2f(E[(lrb + 2) * 132]);
    T[(hl * 2 + pw) * 132 + cl] = v;
  }
  __syncthreads();

  float mean = 0.f, rstd = 0.f;
  if (PASS == 1) { mean = msh[0]; rstd = msh[1]; }
  float s1 = 0.f, s2 = 0.f;
  for (int hi = t; hi < 4096; hi += 256) {
    int hl = hi >> 7, w2 = (hi & 127) * 2;
    const float* T0 = &T[(hl * 2) * 132];
    const float* T1 = &T[(hl * 2 + 1) * 132];
    int n = w2 >> 1;
    float ve = T1[n] + 3.f * T0[n + 1] + 3.f * T1[n + 1] + T0[n + 2];
    float vo = T0[n + 1] + 3.f * T1[n + 1] + 3.f * T0[n + 2] + T1[n + 2];
    ve *= 0.0625f; vo *= 0.0625f;
    if (PASS == 0) {
      s1 += ve + vo; s2 += ve * ve + vo * vo;
    } else {
      int h = 32 * g + hl;
      int par = ((h >> 3) & 1) * 2 + ((w2 >> 3) & 1);   // w2 even: w2,w2+1 share
      int px2 = (h >> 4) * 16 + (w2 >> 4);
      float msw = swp[((size_t)(b * 256 + co) * 4 + par) * 256 + px2];
      float msb = swp[((size_t)(b * 256 + 128 + co) * 4 + par) * 256 + px2];
      float f1 = (1.f + 0.3f * msw) * rstd;
      float f0 = 0.3f * msb - mean * f1;
      float2 o = make_float2(ve * f1 + f0, vo * f1 + f0);
      *(float2*)(dout + ((size_t)bc * 256 + h) * 256 + w2) = o;
    }
  }
  if (PASS == 0) {
    #pragma unroll
    for (int m = 32; m; m >>= 1) { s1 += __shfl_xor(s1, m, 64); s2 += __shfl_xor(s2, m, 64); }
    if (lane == 0) { rb2[wid * 2] = s1; rb2[wid * 2 + 1] = s2; }
    __syncthreads();
    if (t == 0) {
      part[((size_t)bc * 8 + g) * 2]     = rb2[0] + rb2[2] + rb2[4] + rb2[6];
      part[((size_t)bc * 8 + g) * 2 + 1] = rb2[1] + rb2[3] + rb2[5] + rb2[7];
    }
  }
}

extern "C" void kernel_launch(void* const* d_in, const int* in_sizes, int n_in,
                              void* d_out, int out_size, void* d_ws, size_t ws_size,
                              hipStream_t stream) {
  const float* x      = (const float*)d_in[0];
  const float* style  = (const float*)d_in[1];
  const float* weight = (const float*)d_in[2];
  const float* lin_w  = (const float*)d_in[3];
  const float* lin_b  = (const float*)d_in[4];
  const float* cw_w   = (const float*)d_in[5];
  const float* cw_b   = (const float*)d_in[6];
  const float* cb_w   = (const float*)d_in[7];
  const float* cb_b   = (const float*)d_in[8];
  float* out = (float*)d_out;
  char* ws = (char*)d_ws;

  short*          kbu     = (short*)(ws);                     //   294,912
  short*          kb2     = (short*)(ws + 294912);            // 1,048,576
  unsigned short* xt      = (unsigned short*)(ws + 1343488);  // 33,554,432
  unsigned short* smap_bf = (unsigned short*)(ws + 34897920); //   524,288
  float*          swp     = (float*)(ws + 35422208);          // 8,388,608
  float*          part    = (float*)(ws + 43810816);          //   131,072
  unsigned short* out1    = (unsigned short*)(ws + 43941888); // 140,574,720 (end 184.5MB)

  prep_all<<<dim3(4160), dim3(256), 0, stream>>>(
      weight, cw_w, cb_w, x, style, lin_w, lin_b, kbu, kb2, xt, smap_bf);
  modconv_kernel<<<dim3(4, 8), dim3(512), 73984, stream>>>(smap_bf, kb2, cw_b, cb_b, swp);
  convt_kernel<<<dim3(5, 65, 8), dim3(256), 0, stream>>>(xt, kbu, out1);
  blur_kernel<0><<<dim3(8, 128, 8), dim3(256), 0, stream>>>(out1, part, swp, out);
  blur_kernel<1><<<dim3(8, 128, 8), dim3(256), 0, stream>>>(out1, part, swp, out);
}

// Round 8
// 378.088 us; speedup vs baseline: 2.1271x; 1.3712x over previous
//
#include <hip/hip_runtime.h>
#include <cstdint>

// B=8, Cin=Cout=128, x 128x128 -> out 256x256.
#define SCALE_MAIN 0.029462782549439483f   // 1/sqrt(128*9)
#define LSCALE     0.044194173824159223f   // 1/sqrt(512)
#define CSCALE     0.029462782549439483f   // 1/sqrt(128*9)

typedef __attribute__((ext_vector_type(8))) short bf16x8;
typedef __attribute__((ext_vector_type(4))) float f32x4;
typedef __attribute__((ext_vector_type(2))) unsigned int u32x2;
typedef __attribute__((ext_vector_type(4))) unsigned int u32x4;

static __device__ __forceinline__ float lrelu_s2(float v) {
  return (v > 0.f ? v : 0.2f * v) * 1.4142135623730951f;
}
static __device__ __forceinline__ unsigned short f2bf(float f) {
  unsigned int u = __builtin_bit_cast(unsigned int, f);
  u += 0x7FFFu + ((u >> 16) & 1u);
  return (unsigned short)(u >> 16);
}
static __device__ __forceinline__ float s2f(unsigned short s) {
  return __builtin_bit_cast(float, (unsigned int)s << 16);
}

// ---------------------------------------------------------------------------
// K1 prep_all: [0,2048) kb2 | [2048,2624) kbu | [2624,3648) xpose | rest style
// (verbatim -- verified)
// ---------------------------------------------------------------------------
__global__ __launch_bounds__(256) void prep_all(
    const float* __restrict__ weight, const float* __restrict__ cw_w,
    const float* __restrict__ cb_w, const float* __restrict__ x,
    const float* __restrict__ style, const float* __restrict__ lin_w,
    const float* __restrict__ lin_b, short* __restrict__ kbu,
    short* __restrict__ kb2, unsigned short* __restrict__ xt,
    unsigned short* __restrict__ smap_bf) {
  int bid = blockIdx.x;
  int t = threadIdx.x;
  if (bid < 2048) {
    int idx = bid * 256 + t;
    int j   = idx & 7;
    int co  = (idx >> 3) & 255;
    int kc  = (idx >> 11) & 63;
    int par = idx >> 17;
    int k = kc * 8 + j;
    int t2 = k >> 7, ci = k & 127;
    int dy2 = t2 >> 1, dx2 = t2 & 1;
    int ph = par >> 1, pw = par & 1;
    const float* wsrc = (co < 128)
        ? cw_w + ((size_t)co * 128 + ci) * 9
        : cb_w + ((size_t)(co - 128) * 128 + ci) * 9;
    float acc = 0.f;
    #pragma unroll
    for (int kh = 0; kh < 3; ++kh) {
      bool okh = dy2 == 0 ? (ph == 0 ? kh == 0 : kh <= 1)
                          : (ph == 0 ? kh >= 1 : kh == 2);
      if (!okh) continue;
      #pragma unroll
      for (int kw = 0; kw < 3; ++kw) {
        bool okw = dx2 == 0 ? (pw == 0 ? kw == 0 : kw <= 1)
                            : (pw == 0 ? kw >= 1 : kw == 2);
        if (okw) acc += wsrc[kh * 3 + kw];
      }
    }
    kb2[idx] = (short)f2bf(acc * CSCALE);
  } else if (bid < 2624) {
    int idx2 = (bid - 2048) * 256 + t;       // < 147456
    int j    = idx2 & 7;
    int co   = (idx2 >> 3) & 127;
    int ksub = (idx2 >> 10) & 3;
    int s    = (idx2 >> 12) & 3;
    int tp   = idx2 >> 14;                   // tap 0..8
    int ci = s * 32 + ksub * 8 + j;
    int wr = (tp == 0 || tp == 1 || tp == 4) ? 2
           : (tp >= 6) ? 1 : 0;
    int wc = (tp == 0 || tp == 2 || tp == 6) ? 2
           : (tp == 4 || tp == 5 || tp == 8) ? 1 : 0;
    float v = weight[((size_t)(co * 128 + ci)) * 9 + wr * 3 + wc] * SCALE_MAIN;
    kbu[idx2] = (short)f2bf(v);
  } else if (bid < 3648) {
    int q = bid - 2624;
    int y = q & 127, b = q >> 7;
    __shared__ unsigned short tl[128 * 134];
    #pragma unroll 4
    for (int i = 0; i < 16; ++i) {
      int c = t + i * 256;
      int ci = c >> 5, x4 = c & 31;
      f32x4 v = *(const f32x4*)(x + (size_t)(b * 128 + ci) * 16384 + y * 128 + x4 * 4);
      unsigned int* dst = (unsigned int*)(tl + ci * 134 + x4 * 4);
      dst[0] = (unsigned int)f2bf(v.x) | ((unsigned int)f2bf(v.y) << 16);
      dst[1] = (unsigned int)f2bf(v.z) | ((unsigned int)f2bf(v.w) << 16);
    }
    __syncthreads();
    #pragma unroll 2
    for (int i = 0; i < 8; ++i) {
      int c = t + i * 256;
      int xcol = c >> 4, sub = c & 15;
      unsigned short u[8];
      #pragma unroll
      for (int j = 0; j < 8; ++j) u[j] = tl[(sub * 8 + j) * 134 + xcol];
      u32x4 o;
      o.x = (unsigned int)u[0] | ((unsigned int)u[1] << 16);
      o.y = (unsigned int)u[2] | ((unsigned int)u[3] << 16);
      o.z = (unsigned int)u[4] | ((unsigned int)u[5] << 16);
      o.w = (unsigned int)u[6] | ((unsigned int)u[7] << 16);
      *(u32x4*)(xt + ((size_t)(b * 128 + y) * 128 + xcol) * 128 + sub * 8) = o;
    }
  } else {
    int wid = t >> 6, lane = t & 63;
    int gw = (bid - 3648) * 4 + wid;
    const float4* st4 = (const float4*)style;
    float s[8][8];
    #pragma unroll
    for (int b = 0; b < 8; ++b) {
      float4 a0 = st4[b * 128 + lane * 2];
      float4 a1 = st4[b * 128 + lane * 2 + 1];
      s[b][0] = a0.x; s[b][1] = a0.y; s[b][2] = a0.z; s[b][3] = a0.w;
      s[b][4] = a1.x; s[b][5] = a1.y; s[b][6] = a1.z; s[b][7] = a1.w;
    }
    for (int rr = 0; rr < 16; ++rr) {
      int j = gw * 16 + rr;
      const float4* wp = (const float4*)(lin_w + (size_t)j * 512);
      float4 w0 = wp[lane * 2], w1 = wp[lane * 2 + 1];
      float acc[8];
      #pragma unroll
      for (int b = 0; b < 8; ++b) {
        acc[b] = w0.x * s[b][0] + w0.y * s[b][1] + w0.z * s[b][2] + w0.w * s[b][3]
               + w1.x * s[b][4] + w1.y * s[b][5] + w1.z * s[b][6] + w1.w * s[b][7];
      }
      #pragma unroll
      for (int m = 32; m; m >>= 1) {
        #pragma unroll
        for (int b = 0; b < 8; ++b) acc[b] += __shfl_xor(acc[b], m, 64);
      }
      if (lane == 0) {
        float bias = lin_b[j];
        int ci = j >> 8, sp = j & 255;
        #pragma unroll
        for (int b = 0; b < 8; ++b)
          smap_bf[(size_t)(b * 256 + sp) * 128 + ci] =
              f2bf(lrelu_s2(acc[b] * LSCALE + bias));
      }
    }
  }
}

// ---------------------------------------------------------------------------
// K2 modconv (verbatim -- verified)
// ---------------------------------------------------------------------------
__global__ __launch_bounds__(512, 2) void modconv_kernel(
    const unsigned short* __restrict__ smap_bf, const short* __restrict__ kb2,
    const float* __restrict__ cw_b, const float* __restrict__ cb_b,
    float* __restrict__ swp) {
  extern __shared__ __align__(16) char dsm[];   // 73984 B
  int par = blockIdx.x, b = blockIdx.y;
  int ph = par >> 1, pw = par & 1;
  int t = threadIdx.x, lane = t & 63, w = t >> 6;
  int q = w >> 1, ch = w & 1;
  int m15 = lane & 15, ksub = lane >> 4;

  for (int c = t; c < 4624; c += 512) {
    int s = c >> 4, cch = c & 15;
    int rr = s / 17, cc = s - rr * 17;
    int gr = rr - 1 + ph, gc = cc - 1 + pw;
    u32x4 v = {0u, 0u, 0u, 0u};
    if ((unsigned)gr < 16u && (unsigned)gc < 16u)
      v = *(const u32x4*)(smap_bf + ((size_t)(b * 256 + gr * 16 + gc) * 128 + cch * 8));
    int phys = (cch + s) & 15;
    *(u32x4*)(dsm + s * 256 + phys * 16) = v;
  }
  __syncthreads();

  const bf16x8* kbv = (const bf16x8*)kb2;
  f32x4 acc[4][8];
  #pragma unroll
  for (int i = 0; i < 4; ++i)
  #pragma unroll
  for (int j = 0; j < 8; ++j) acc[i][j] = (f32x4){0.f, 0.f, 0.f, 0.f};

  for (int s = 0; s < 16; ++s) {
    int t2 = s >> 2, dy2 = t2 >> 1, dx2 = t2 & 1;
    int cch = (s & 3) * 4 + ksub;
    bf16x8 av[4];
    #pragma unroll
    for (int mf = 0; mf < 4; ++mf) {
      int i = q * 4 + mf;
      int ssp = (i + dy2) * 17 + (m15 + dx2);
      int phys = (cch + ssp) & 15;
      av[mf] = *(const bf16x8*)(dsm + ssp * 256 + phys * 16);
    }
    #pragma unroll
    for (int nf = 0; nf < 8; ++nf) {
      bf16x8 bv = kbv[(size_t)((par * 64 + s * 4 + ksub) * 256 + ch * 128 + nf * 16 + m15)];
      #pragma unroll
      for (int mf = 0; mf < 4; ++mf)
        acc[mf][nf] = __builtin_amdgcn_mfma_f32_16x16x32_bf16(av[mf], bv, acc[mf][nf], 0, 0, 0);
    }
  }

  int jbase = ksub * 4;
  #pragma unroll
  for (int nf = 0; nf < 8; ++nf) {
    int co = ch * 128 + nf * 16 + m15;
    float bias = (co < 128) ? cw_b[co] : cb_b[co - 128];
    #pragma unroll
    for (int mf = 0; mf < 4; ++mf) {
      int i = q * 4 + mf;
      #pragma unroll
      for (int r = 0; r < 4; ++r) {
        int px = i * 16 + jbase + r;
        swp[((size_t)(b * 256 + co) * 4 + par) * 256 + px] = acc[mf][nf][r] + bias;
      }
    }
  }
}

// ---------------------------------------------------------------------------
// K3 convt v2 (verbatim -- verified): unfused transposed conv -> 4 parity
// planes bf16, out1[b][pl][co][130][132].
// ---------------------------------------------------------------------------
__global__ __launch_bounds__(256, 2) void convt_kernel(
    const unsigned short* __restrict__ xt, const short* __restrict__ kbu,
    unsigned short* __restrict__ out1) {
  __shared__ __align__(16) char smem[26112];   // A-tile 102*256; reused as eps
  int cg = blockIdx.x, rp = blockIdx.y, b = blockIdx.z;
  int t = threadIdx.x, lane = t & 63, w = t >> 6;
  int m15 = lane & 15, ksub = lane >> 4;
  int pl = (w + cg + rp) & 3;                  // wave's plane, SIMD-balanced
  int tstart = (pl == 0) ? 0 : 2 + 2 * pl;     // {0,4,6,8}
  int nst = 16 >> ((pl + 1) >> 1);             // {16,8,8,4}

  const char* xtc = (const char*)xt;
  for (int c = t; c < 1632; c += 256) {
    int spos = c >> 4, sub = c & 15;
    int lr = spos / 34, lc = spos - lr * 34;
    int y = 2 * rp - 1 + lr, xg = 32 * cg - 1 + lc;
    f32x4 v = {0.f, 0.f, 0.f, 0.f};
    if ((unsigned)y < 128u && (unsigned)xg < 128u)
      v = *(const f32x4*)(xtc + ((size_t)((b * 128 + y) * 128 + xg)) * 256 + sub * 16);
    int phys = (sub & 8) | ((sub ^ spos) & 7);
    *(f32x4*)(smem + spos * 256 + phys * 16) = v;
  }
  __syncthreads();

  const bf16x8* kbv = (const bf16x8*)kbu;
  f32x4 acc[4][8];
  #pragma unroll
  for (int i = 0; i < 4; ++i)
  #pragma unroll
  for (int j = 0; j < 8; ++j) acc[i][j] = (f32x4){0.f, 0.f, 0.f, 0.f};

  auto LD = [&](int s, bf16x8* av, bf16x8* bv) {
    int tap = tstart + (s >> 2);
    int du = -((0x13 >> tap) & 1);
    int dv = -((0x45 >> tap) & 1);
    int cc = s & 3;
    int c = cc * 4 + ksub;
    #pragma unroll
    for (int mf = 0; mf < 4; ++mf) {
      int spos = ((mf >> 1) + du + 1) * 34 + (mf & 1) * 16 + m15 + dv + 1;
      int phys = (c & 8) | ((c ^ spos) & 7);
      av[mf] = *(const bf16x8*)(smem + spos * 256 + phys * 16);
    }
    int bb = tap * 2048 + cc * 512 + ksub * 128 + m15;
    #pragma unroll
    for (int nf = 0; nf < 8; ++nf) bv[nf] = kbv[bb + nf * 16];
  };
  auto MM = [&](bf16x8* av, bf16x8* bv) {
    __builtin_amdgcn_s_setprio(1);
    #pragma unroll
    for (int nf = 0; nf < 8; ++nf)
    #pragma unroll
    for (int mf = 0; mf < 4; ++mf)
      acc[mf][nf] = __builtin_amdgcn_mfma_f32_16x16x32_bf16(av[mf], bv[nf], acc[mf][nf], 0, 0, 0);
    __builtin_amdgcn_s_setprio(0);
  };

  bf16x8 aA[4], bA[8], aB[4], bB[8];
  LD(0, aA, bA);
  for (int s = 0; s + 2 <= nst; s += 2) {
    LD(s + 1, aB, bB);
    MM(aA, bA);
    if (s + 2 < nst) LD(s + 2, aA, bA);
    MM(aB, bB);
  }

  __syncthreads();
  float* eps = (float*)smem;                   // [pl 4][px 64][17]
  int t63 = t & 63, wpl = t >> 6;
  #pragma unroll
  for (int nf = 0; nf < 8; ++nf) {
    #pragma unroll
    for (int mf = 0; mf < 4; ++mf)
    #pragma unroll
    for (int r = 0; r < 4; ++r)
      eps[(pl * 64 + mf * 16 + ksub * 4 + r) * 17 + m15] = acc[mf][nf][r];
    __syncthreads();
    #pragma unroll
    for (int k = 0; k < 4; ++k) {
      int slot = k * 64 + t63;                 // [co16:4][pr:1][ch:3]
      int co16 = slot >> 4, pr = (slot >> 3) & 1, ch = slot & 7;
      float v0 = eps[(wpl * 64 + pr * 32 + ch * 4 + 0) * 17 + co16];
      float v1 = eps[(wpl * 64 + pr * 32 + ch * 4 + 1) * 17 + co16];
      float v2 = eps[(wpl * 64 + pr * 32 + ch * 4 + 2) * 17 + co16];
      float v3 = eps[(wpl * 64 + pr * 32 + ch * 4 + 3) * 17 + co16];
      u32x2 o;
      o.x = (unsigned int)f2bf(v0) | ((unsigned int)f2bf(v1) << 16);
      o.y = (unsigned int)f2bf(v2) | ((unsigned int)f2bf(v3) << 16);
      int co = nf * 16 + co16;
      int r = 2 * rp + pr;
      size_t ob = (((size_t)(b * 4 + wpl) * 128 + co) * 130 + r) * 132
                + 32 * cg + ch * 4;
      if (cg < 4 || ch == 0) *(u32x2*)(out1 + ob) = o;
    }
    __syncthreads();
  }
}

// ---------------------------------------------------------------------------
// K4/K5 blur v3: separable [1,3,3,1]^2/16 over parity planes. Division-free
// affine indexing; half-strip T buffer (4 blocks/CU); PASS1 swp cached in LDS.
// Block (g,co,b): out rows [32g,32g+32) x all 256 cols.
// ---------------------------------------------------------------------------
template <int PASS>
__global__ __launch_bounds__(256) void blur_kernel(
    const unsigned short* __restrict__ out1, float* __restrict__ part,
    const float* __restrict__ swp, float* __restrict__ dout) {
  __shared__ unsigned short S[4][18][132];     // 19008 B, plane rows rb..rb+17
  __shared__ float T[32][132];                 // 16896 B, half-strip vertical
  __shared__ float lsw[4][32], lsb[4][32];     // 1024 B, PASS1 modulation
  __shared__ float msh[2];
  __shared__ float rb2[8];
  int g = blockIdx.x, co = blockIdx.y, b = blockIdx.z;
  int t = threadIdx.x, lane = t & 63, wid = t >> 6;
  int bc = b * 128 + co;

  if (PASS == 1) {
    if (t == 0) {
      float a1 = 0.f, a2 = 0.f;
      #pragma unroll
      for (int i = 0; i < 8; ++i) {
        a1 += part[((size_t)bc * 8 + i) * 2];
        a2 += part[((size_t)bc * 8 + i) * 2 + 1];
      }
      float mean = a1 * (1.f / 65536.f);
      float var = a2 * (1.f / 65536.f) - mean * mean;
      msh[0] = mean; msh[1] = rsqrtf(var + 1e-5f);
    }
    {   // stage swp cache: [which][par][hrow*16+wcol]
      int which = t >> 7;
      int par = (t >> 5) & 3;
      int idx = t & 31;
      int hrow = idx >> 4, wcol = idx & 15;
      int px2 = (2 * g + hrow) * 16 + wcol;
      float v = swp[((size_t)(b * 256 + which * 128 + co) * 4 + par) * 256 + px2];
      if (which == 0) lsw[par][idx] = v; else lsb[par][idx] = v;
    }
  }

  // ---- stage S: 4 planes x 18 rows [16g-1 .. 16g+16] x 132 cols ----
  int rbase = 16 * g - 1;
  for (int i = t; i < 2376; i += 256) {
    int pl = i / 594; int rem = i - pl * 594;
    int lr = rem / 33; int lc8 = rem - lr * 33;
    int r = rbase + lr;
    u32x2 v = {0u, 0u};
    if (r >= 0)
      v = *(const u32x2*)(out1 + ((size_t)((b * 4 + pl) * 128 + co) * 130 + r) * 132 + lc8 * 4);
    *(u32x2*)(&S[0][0][0] + (pl * 18 + lr) * 132 + lc8 * 4) = v;
  }
  if (t < 32) T[t][0] = 0.f;                   // cl=0 <-> plane col -1 = 0
  __syncthreads();

  float mean = 0.f, rstd = 0.f;
  if (PASS == 1) { mean = msh[0]; rstd = msh[1]; }
  float s1 = 0.f, s2 = 0.f;

  #pragma unroll
  for (int half = 0; half < 2; ++half) {
    if (half == 1) __syncthreads();            // horiz(0) done before T rewrite
    // ---- vertical: thread -> (pw = t&1, pc = t>>1); imm-offset reads ----
    {
      int pw = t & 1, pc = t >> 1;             // pc 0..127
      const unsigned short* E = &S[pw][0][pc];
      const unsigned short* O = &S[2 + pw][0][pc];
      float* Tr = &T[0][0] + pw * 132 + pc + 1;
      #pragma unroll
      for (int k = 0; k < 16; ++k) {
        int hl = half * 16 + k;
        int lrb = (hl + 1) >> 1;
        float v;
        if (hl & 1)
          v = (s2f(E[lrb * 132]) + s2f(O[(lrb + 1) * 132]))
            + 3.f * (s2f(O[lrb * 132]) + s2f(E[(lrb + 1) * 132]));
        else
          v = (s2f(O[lrb * 132]) + s2f(E[(lrb + 2) * 132]))
            + 3.f * (s2f(E[(lrb + 1) * 132]) + s2f(O[(lrb + 1) * 132]));
        Tr[k * 264] = v;
      }
      if (t < 2) {                             // leftover col pc=128 (cl=129)
        const unsigned short* E2 = &S[t][0][128];
        const unsigned short* O2 = &S[2 + t][0][128];
        float* Tr2 = &T[0][0] + t * 132 + 129;
        #pragma unroll
        for (int k = 0; k < 16; ++k) {
          int hl = half * 16 + k;
          int lrb = (hl + 1) >> 1;
          float v;
          if (hl & 1)
            v = (s2f(E2[lrb * 132]) + s2f(O2[(lrb + 1) * 132]))
              + 3.f * (s2f(O2[lrb * 132]) + s2f(E2[(lrb + 1) * 132]));
          else
            v = (s2f(O2[lrb * 132]) + s2f(E2[(lrb + 2) * 132]))
              + 3.f * (s2f(E2[(lrb + 1) * 132]) + s2f(O2[(lrb + 1) * 132]));
          Tr2[k * 264] = v;
        }
      }
    }
    __syncthreads();
    // ---- horizontal: thread -> (n = t&127, hh = t>>7) ----
    {
      int n = t & 127, hh = t >> 7;
      #pragma unroll
      for (int k = 0; k < 8; ++k) {
        int klocal = k * 2 + hh;               // 0..15
        const float* T0 = &T[klocal * 2][0];
        const float* T1 = &T[klocal * 2 + 1][0];
        float t0n = T0[n], t0n1 = T0[n + 1], t0n2 = T0[n + 2];
        float t1n = T1[n], t1n1 = T1[n + 1], t1n2 = T1[n + 2];
        float ve = ((t1n + t0n2) + 3.f * (t0n1 + t1n1)) * 0.0625f;
        float vo = ((t0n1 + t1n2) + 3.f * (t1n1 + t0n2)) * 0.0625f;
        if (PASS == 0) {
          s1 += ve + vo; s2 += ve * ve + vo * vo;
        } else {
          int hl = half * 16 + klocal;
          int h = 32 * g + hl;
          int par = ((klocal >> 3) & 1) * 2 + ((n >> 2) & 1);
          int lidx = half * 16 + (n >> 3);
          float msw = lsw[par][lidx], msb = lsb[par][lidx];
          float f1 = (1.f + 0.3f * msw) * rstd;
          float f0 = 0.3f * msb - mean * f1;
          float2 o = make_float2(ve * f1 + f0, vo * f1 + f0);
          *(float2*)(dout + ((size_t)bc * 256 + h) * 256 + 2 * n) = o;
        }
      }
    }
  }

  if (PASS == 0) {
    #pragma unroll
    for (int m = 32; m; m >>= 1) { s1 += __shfl_xor(s1, m, 64); s2 += __shfl_xor(s2, m, 64); }
    if (lane == 0) { rb2[wid * 2] = s1; rb2[wid * 2 + 1] = s2; }
    __syncthreads();
    if (t == 0) {
      part[((size_t)bc * 8 + g) * 2]     = rb2[0] + rb2[2] + rb2[4] + rb2[6];
      part[((size_t)bc * 8 + g) * 2 + 1] = rb2[1] + rb2[3] + rb2[5] + rb2[7];
    }
  }
}

extern "C" void kernel_launch(void* const* d_in, const int* in_sizes, int n_in,
                              void* d_out, int out_size, void* d_ws, size_t ws_size,
                              hipStream_t stream) {
  const float* x      = (const float*)d_in[0];
  const float* style  = (const float*)d_in[1];
  const float* weight = (const float*)d_in[2];
  const float* lin_w  = (const float*)d_in[3];
  const float* lin_b  = (const float*)d_in[4];
  const float* cw_w   = (const float*)d_in[5];
  const float* cw_b   = (const float*)d_in[6];
  const float* cb_w   = (const float*)d_in[7];
  const float* cb_b   = (const float*)d_in[8];
  float* out = (float*)d_out;
  char* ws = (char*)d_ws;

  short*          kbu     = (short*)(ws);                     //   294,912
  short*          kb2     = (short*)(ws + 294912);            // 1,048,576
  unsigned short* xt      = (unsigned short*)(ws + 1343488);  // 33,554,432
  unsigned short* smap_bf = (unsigned short*)(ws + 34897920); //   524,288
  float*          swp     = (float*)(ws + 35422208);          // 8,388,608
  float*          part    = (float*)(ws + 43810816);          //   131,072
  unsigned short* out1    = (unsigned short*)(ws + 43941888); // 140,574,720 (end 184.5MB)

  prep_all<<<dim3(4160), dim3(256), 0, stream>>>(
      weight, cw_w, cb_w, x, style, lin_w, lin_b, kbu, kb2, xt, smap_bf);
  modconv_kernel<<<dim3(4, 8), dim3(512), 73984, stream>>>(smap_bf, kb2, cw_b, cb_b, swp);
  convt_kernel<<<dim3(5, 65, 8), dim3(256), 0, stream>>>(xt, kbu, out1);
  blur_kernel<0><<<dim3(8, 128, 8), dim3(256), 0, stream>>>(out1, part, swp, out);
  blur_kernel<1><<<dim3(8, 128, 8), dim3(256), 0, stream>>>(out1, part, swp, out);
}

// Round 9
// 372.219 us; speedup vs baseline: 2.1606x; 1.0158x over previous
//
#include <hip/hip_runtime.h>
#include <cstdint>

// B=8, Cin=Cout=128, x 128x128 -> out 256x256.
#define SCALE_MAIN 0.029462782549439483f   // 1/sqrt(128*9)
#define LSCALE     0.044194173824159223f   // 1/sqrt(512)
#define CSCALE     0.029462782549439483f   // 1/sqrt(128*9)

typedef __attribute__((ext_vector_type(8))) short bf16x8;
typedef __attribute__((ext_vector_type(4))) float f32x4;
typedef __attribute__((ext_vector_type(2))) unsigned int u32x2;
typedef __attribute__((ext_vector_type(4))) unsigned int u32x4;

static __device__ __forceinline__ float lrelu_s2(float v) {
  return (v > 0.f ? v : 0.2f * v) * 1.4142135623730951f;
}
static __device__ __forceinline__ unsigned short f2bf(float f) {
  unsigned int u = __builtin_bit_cast(unsigned int, f);
  u += 0x7FFFu + ((u >> 16) & 1u);
  return (unsigned short)(u >> 16);
}
static __device__ __forceinline__ float s2f(unsigned short s) {
  return __builtin_bit_cast(float, (unsigned int)s << 16);
}
static __device__ __forceinline__ float lo16(unsigned int v) {
  return __builtin_bit_cast(float, v << 16);
}
static __device__ __forceinline__ float hi16(unsigned int v) {
  return __builtin_bit_cast(float, v & 0xFFFF0000u);
}

// ---------------------------------------------------------------------------
// K1 prep_all: [0,2048) kb2 | [2048,2624) kbu | [2624,3648) xpose | rest style
// (verbatim -- verified)
// ---------------------------------------------------------------------------
__global__ __launch_bounds__(256) void prep_all(
    const float* __restrict__ weight, const float* __restrict__ cw_w,
    const float* __restrict__ cb_w, const float* __restrict__ x,
    const float* __restrict__ style, const float* __restrict__ lin_w,
    const float* __restrict__ lin_b, short* __restrict__ kbu,
    short* __restrict__ kb2, unsigned short* __restrict__ xt,
    unsigned short* __restrict__ smap_bf) {
  int bid = blockIdx.x;
  int t = threadIdx.x;
  if (bid < 2048) {
    int idx = bid * 256 + t;
    int j   = idx & 7;
    int co  = (idx >> 3) & 255;
    int kc  = (idx >> 11) & 63;
    int par = idx >> 17;
    int k = kc * 8 + j;
    int t2 = k >> 7, ci = k & 127;
    int dy2 = t2 >> 1, dx2 = t2 & 1;
    int ph = par >> 1, pw = par & 1;
    const float* wsrc = (co < 128)
        ? cw_w + ((size_t)co * 128 + ci) * 9
        : cb_w + ((size_t)(co - 128) * 128 + ci) * 9;
    float acc = 0.f;
    #pragma unroll
    for (int kh = 0; kh < 3; ++kh) {
      bool okh = dy2 == 0 ? (ph == 0 ? kh == 0 : kh <= 1)
                          : (ph == 0 ? kh >= 1 : kh == 2);
      if (!okh) continue;
      #pragma unroll
      for (int kw = 0; kw < 3; ++kw) {
        bool okw = dx2 == 0 ? (pw == 0 ? kw == 0 : kw <= 1)
                            : (pw == 0 ? kw >= 1 : kw == 2);
        if (okw) acc += wsrc[kh * 3 + kw];
      }
    }
    kb2[idx] = (short)f2bf(acc * CSCALE);
  } else if (bid < 2624) {
    int idx2 = (bid - 2048) * 256 + t;       // < 147456
    int j    = idx2 & 7;
    int co   = (idx2 >> 3) & 127;
    int ksub = (idx2 >> 10) & 3;
    int s    = (idx2 >> 12) & 3;
    int tp   = idx2 >> 14;                   // tap 0..8
    int ci = s * 32 + ksub * 8 + j;
    int wr = (tp == 0 || tp == 1 || tp == 4) ? 2
           : (tp >= 6) ? 1 : 0;
    int wc = (tp == 0 || tp == 2 || tp == 6) ? 2
           : (tp == 4 || tp == 5 || tp == 8) ? 1 : 0;
    float v = weight[((size_t)(co * 128 + ci)) * 9 + wr * 3 + wc] * SCALE_MAIN;
    kbu[idx2] = (short)f2bf(v);
  } else if (bid < 3648) {
    int q = bid - 2624;
    int y = q & 127, b = q >> 7;
    __shared__ unsigned short tl[128 * 134];
    #pragma unroll 4
    for (int i = 0; i < 16; ++i) {
      int c = t + i * 256;
      int ci = c >> 5, x4 = c & 31;
      f32x4 v = *(const f32x4*)(x + (size_t)(b * 128 + ci) * 16384 + y * 128 + x4 * 4);
      unsigned int* dst = (unsigned int*)(tl + ci * 134 + x4 * 4);
      dst[0] = (unsigned int)f2bf(v.x) | ((unsigned int)f2bf(v.y) << 16);
      dst[1] = (unsigned int)f2bf(v.z) | ((unsigned int)f2bf(v.w) << 16);
    }
    __syncthreads();
    #pragma unroll 2
    for (int i = 0; i < 8; ++i) {
      int c = t + i * 256;
      int xcol = c >> 4, sub = c & 15;
      unsigned short u[8];
      #pragma unroll
      for (int j = 0; j < 8; ++j) u[j] = tl[(sub * 8 + j) * 134 + xcol];
      u32x4 o;
      o.x = (unsigned int)u[0] | ((unsigned int)u[1] << 16);
      o.y = (unsigned int)u[2] | ((unsigned int)u[3] << 16);
      o.z = (unsigned int)u[4] | ((unsigned int)u[5] << 16);
      o.w = (unsigned int)u[6] | ((unsigned int)u[7] << 16);
      *(u32x4*)(xt + ((size_t)(b * 128 + y) * 128 + xcol) * 128 + sub * 8) = o;
    }
  } else {
    int wid = t >> 6, lane = t & 63;
    int gw = (bid - 3648) * 4 + wid;
    const float4* st4 = (const float4*)style;
    float s[8][8];
    #pragma unroll
    for (int b = 0; b < 8; ++b) {
      float4 a0 = st4[b * 128 + lane * 2];
      float4 a1 = st4[b * 128 + lane * 2 + 1];
      s[b][0] = a0.x; s[b][1] = a0.y; s[b][2] = a0.z; s[b][3] = a0.w;
      s[b][4] = a1.x; s[b][5] = a1.y; s[b][6] = a1.z; s[b][7] = a1.w;
    }
    for (int rr = 0; rr < 16; ++rr) {
      int j = gw * 16 + rr;
      const float4* wp = (const float4*)(lin_w + (size_t)j * 512);
      float4 w0 = wp[lane * 2], w1 = wp[lane * 2 + 1];
      float acc[8];
      #pragma unroll
      for (int b = 0; b < 8; ++b) {
        acc[b] = w0.x * s[b][0] + w0.y * s[b][1] + w0.z * s[b][2] + w0.w * s[b][3]
               + w1.x * s[b][4] + w1.y * s[b][5] + w1.z * s[b][6] + w1.w * s[b][7];
      }
      #pragma unroll
      for (int m = 32; m; m >>= 1) {
        #pragma unroll
        for (int b = 0; b < 8; ++b) acc[b] += __shfl_xor(acc[b], m, 64);
      }
      if (lane == 0) {
        float bias = lin_b[j];
        int ci = j >> 8, sp = j & 255;
        #pragma unroll
        for (int b = 0; b < 8; ++b)
          smap_bf[(size_t)(b * 256 + sp) * 128 + ci] =
              f2bf(lrelu_s2(acc[b] * LSCALE + bias));
      }
    }
  }
}

// ---------------------------------------------------------------------------
// K2 modconv (verbatim -- verified)
// ---------------------------------------------------------------------------
__global__ __launch_bounds__(512, 2) void modconv_kernel(
    const unsigned short* __restrict__ smap_bf, const short* __restrict__ kb2,
    const float* __restrict__ cw_b, const float* __restrict__ cb_b,
    float* __restrict__ swp) {
  extern __shared__ __align__(16) char dsm[];   // 73984 B
  int par = blockIdx.x, b = blockIdx.y;
  int ph = par >> 1, pw = par & 1;
  int t = threadIdx.x, lane = t & 63, w = t >> 6;
  int q = w >> 1, ch = w & 1;
  int m15 = lane & 15, ksub = lane >> 4;

  for (int c = t; c < 4624; c += 512) {
    int s = c >> 4, cch = c & 15;
    int rr = s / 17, cc = s - rr * 17;
    int gr = rr - 1 + ph, gc = cc - 1 + pw;
    u32x4 v = {0u, 0u, 0u, 0u};
    if ((unsigned)gr < 16u && (unsigned)gc < 16u)
      v = *(const u32x4*)(smap_bf + ((size_t)(b * 256 + gr * 16 + gc) * 128 + cch * 8));
    int phys = (cch + s) & 15;
    *(u32x4*)(dsm + s * 256 + phys * 16) = v;
  }
  __syncthreads();

  const bf16x8* kbv = (const bf16x8*)kb2;
  f32x4 acc[4][8];
  #pragma unroll
  for (int i = 0; i < 4; ++i)
  #pragma unroll
  for (int j = 0; j < 8; ++j) acc[i][j] = (f32x4){0.f, 0.f, 0.f, 0.f};

  for (int s = 0; s < 16; ++s) {
    int t2 = s >> 2, dy2 = t2 >> 1, dx2 = t2 & 1;
    int cch = (s & 3) * 4 + ksub;
    bf16x8 av[4];
    #pragma unroll
    for (int mf = 0; mf < 4; ++mf) {
      int i = q * 4 + mf;
      int ssp = (i + dy2) * 17 + (m15 + dx2);
      int phys = (cch + ssp) & 15;
      av[mf] = *(const bf16x8*)(dsm + ssp * 256 + phys * 16);
    }
    #pragma unroll
    for (int nf = 0; nf < 8; ++nf) {
      bf16x8 bv = kbv[(size_t)((par * 64 + s * 4 + ksub) * 256 + ch * 128 + nf * 16 + m15)];
      #pragma unroll
      for (int mf = 0; mf < 4; ++mf)
        acc[mf][nf] = __builtin_amdgcn_mfma_f32_16x16x32_bf16(av[mf], bv, acc[mf][nf], 0, 0, 0);
    }
  }

  int jbase = ksub * 4;
  #pragma unroll
  for (int nf = 0; nf < 8; ++nf) {
    int co = ch * 128 + nf * 16 + m15;
    float bias = (co < 128) ? cw_b[co] : cb_b[co - 128];
    #pragma unroll
    for (int mf = 0; mf < 4; ++mf) {
      int i = q * 4 + mf;
      #pragma unroll
      for (int r = 0; r < 4; ++r) {
        int px = i * 16 + jbase + r;
        swp[((size_t)(b * 256 + co) * 4 + par) * 256 + px] = acc[mf][nf][r] + bias;
      }
    }
  }
}

// ---------------------------------------------------------------------------
// K3 convt v2 (verbatim -- verified): unfused transposed conv -> 4 parity
// planes bf16, out1[b][pl][co][130][132].
// ---------------------------------------------------------------------------
__global__ __launch_bounds__(256, 2) void convt_kernel(
    const unsigned short* __restrict__ xt, const short* __restrict__ kbu,
    unsigned short* __restrict__ out1) {
  __shared__ __align__(16) char smem[26112];   // A-tile 102*256; reused as eps
  int cg = blockIdx.x, rp = blockIdx.y, b = blockIdx.z;
  int t = threadIdx.x, lane = t & 63, w = t >> 6;
  int m15 = lane & 15, ksub = lane >> 4;
  int pl = (w + cg + rp) & 3;                  // wave's plane, SIMD-balanced
  int tstart = (pl == 0) ? 0 : 2 + 2 * pl;     // {0,4,6,8}
  int nst = 16 >> ((pl + 1) >> 1);             // {16,8,8,4}

  const char* xtc = (const char*)xt;
  for (int c = t; c < 1632; c += 256) {
    int spos = c >> 4, sub = c & 15;
    int lr = spos / 34, lc = spos - lr * 34;
    int y = 2 * rp - 1 + lr, xg = 32 * cg - 1 + lc;
    f32x4 v = {0.f, 0.f, 0.f, 0.f};
    if ((unsigned)y < 128u && (unsigned)xg < 128u)
      v = *(const f32x4*)(xtc + ((size_t)((b * 128 + y) * 128 + xg)) * 256 + sub * 16);
    int phys = (sub & 8) | ((sub ^ spos) & 7);
    *(f32x4*)(smem + spos * 256 + phys * 16) = v;
  }
  __syncthreads();

  const bf16x8* kbv = (const bf16x8*)kbu;
  f32x4 acc[4][8];
  #pragma unroll
  for (int i = 0; i < 4; ++i)
  #pragma unroll
  for (int j = 0; j < 8; ++j) acc[i][j] = (f32x4){0.f, 0.f, 0.f, 0.f};

  auto LD = [&](int s, bf16x8* av, bf16x8* bv) {
    int tap = tstart + (s >> 2);
    int du = -((0x13 >> tap) & 1);
    int dv = -((0x45 >> tap) & 1);
    int cc = s & 3;
    int c = cc * 4 + ksub;
    #pragma unroll
    for (int mf = 0; mf < 4; ++mf) {
      int spos = ((mf >> 1) + du + 1) * 34 + (mf & 1) * 16 + m15 + dv + 1;
      int phys = (c & 8) | ((c ^ spos) & 7);
      av[mf] = *(const bf16x8*)(smem + spos * 256 + phys * 16);
    }
    int bb = tap * 2048 + cc * 512 + ksub * 128 + m15;
    #pragma unroll
    for (int nf = 0; nf < 8; ++nf) bv[nf] = kbv[bb + nf * 16];
  };
  auto MM = [&](bf16x8* av, bf16x8* bv) {
    __builtin_amdgcn_s_setprio(1);
    #pragma unroll
    for (int nf = 0; nf < 8; ++nf)
    #pragma unroll
    for (int mf = 0; mf < 4; ++mf)
      acc[mf][nf] = __builtin_amdgcn_mfma_f32_16x16x32_bf16(av[mf], bv[nf], acc[mf][nf], 0, 0, 0);
    __builtin_amdgcn_s_setprio(0);
  };

  bf16x8 aA[4], bA[8], aB[4], bB[8];
  LD(0, aA, bA);
  for (int s = 0; s + 2 <= nst; s += 2) {
    LD(s + 1, aB, bB);
    MM(aA, bA);
    if (s + 2 < nst) LD(s + 2, aA, bA);
    MM(aB, bB);
  }

  __syncthreads();
  float* eps = (float*)smem;                   // [pl 4][px 64][17]
  int t63 = t & 63, wpl = t >> 6;
  #pragma unroll
  for (int nf = 0; nf < 8; ++nf) {
    #pragma unroll
    for (int mf = 0; mf < 4; ++mf)
    #pragma unroll
    for (int r = 0; r < 4; ++r)
      eps[(pl * 64 + mf * 16 + ksub * 4 + r) * 17 + m15] = acc[mf][nf][r];
    __syncthreads();
    #pragma unroll
    for (int k = 0; k < 4; ++k) {
      int slot = k * 64 + t63;                 // [co16:4][pr:1][ch:3]
      int co16 = slot >> 4, pr = (slot >> 3) & 1, ch = slot & 7;
      float v0 = eps[(wpl * 64 + pr * 32 + ch * 4 + 0) * 17 + co16];
      float v1 = eps[(wpl * 64 + pr * 32 + ch * 4 + 1) * 17 + co16];
      float v2 = eps[(wpl * 64 + pr * 32 + ch * 4 + 2) * 17 + co16];
      float v3 = eps[(wpl * 64 + pr * 32 + ch * 4 + 3) * 17 + co16];
      u32x2 o;
      o.x = (unsigned int)f2bf(v0) | ((unsigned int)f2bf(v1) << 16);
      o.y = (unsigned int)f2bf(v2) | ((unsigned int)f2bf(v3) << 16);
      int co = nf * 16 + co16;
      int r = 2 * rp + pr;
      size_t ob = (((size_t)(b * 4 + wpl) * 128 + co) * 130 + r) * 132
                + 32 * cg + ch * 4;
      if (cg < 4 || ch == 0) *(u32x2*)(out1 + ob) = o;
    }
    __syncthreads();
  }
}

// ---------------------------------------------------------------------------
// K4/K5 blur v4: separable [1,3,3,1]^2/16. Vertical pass processes TWO
// columns per thread via u32 LDS reads (halved LDS-op count); division-free.
// Block (g,co,b): out rows [32g,32g+32) x all 256 cols.
// ---------------------------------------------------------------------------
template <int PASS>
__global__ __launch_bounds__(256) void blur_kernel(
    const unsigned short* __restrict__ out1, float* __restrict__ part,
    const float* __restrict__ swp, float* __restrict__ dout) {
  __shared__ unsigned short S[4][18][132];     // 19008 B, plane rows rb..rb+17
  __shared__ float T[32][132];                 // 16896 B, half-strip vertical
  __shared__ float lsw[4][32], lsb[4][32];     // 1024 B, PASS1 modulation
  __shared__ float msh[2];
  __shared__ float rb2[8];
  int g = blockIdx.x, co = blockIdx.y, b = blockIdx.z;
  int t = threadIdx.x, lane = t & 63, wid = t >> 6;
  int bc = b * 128 + co;

  if (PASS == 1) {
    if (t == 0) {
      float a1 = 0.f, a2 = 0.f;
      #pragma unroll
      for (int i = 0; i < 8; ++i) {
        a1 += part[((size_t)bc * 8 + i) * 2];
        a2 += part[((size_t)bc * 8 + i) * 2 + 1];
      }
      float mean = a1 * (1.f / 65536.f);
      float var = a2 * (1.f / 65536.f) - mean * mean;
      msh[0] = mean; msh[1] = rsqrtf(var + 1e-5f);
    }
    {   // stage swp cache: [which][par][hrow*16+wcol]
      int which = t >> 7;
      int par = (t >> 5) & 3;
      int idx = t & 31;
      int hrow = idx >> 4, wcol = idx & 15;
      int px2 = (2 * g + hrow) * 16 + wcol;
      float v = swp[((size_t)(b * 256 + which * 128 + co) * 4 + par) * 256 + px2];
      if (which == 0) lsw[par][idx] = v; else lsb[par][idx] = v;
    }
  }

  // ---- stage S: 4 planes x 18 rows [16g-1 .. 16g+16] x 132 cols ----
  int rbase = 16 * g - 1;
  for (int i = t; i < 2376; i += 256) {
    int pl = i / 594; int rem = i - pl * 594;
    int lr = rem / 33; int lc8 = rem - lr * 33;
    int r = rbase + lr;
    u32x2 v = {0u, 0u};
    if (r >= 0)
      v = *(const u32x2*)(out1 + ((size_t)((b * 4 + pl) * 128 + co) * 130 + r) * 132 + lc8 * 4);
    *(u32x2*)(&S[0][0][0] + (pl * 18 + lr) * 132 + lc8 * 4) = v;
  }
  if (t < 32) T[t][0] = 0.f;                   // cl=0 <-> plane col -1 = 0
  __syncthreads();

  float mean = 0.f, rstd = 0.f;
  if (PASS == 1) { mean = msh[0]; rstd = msh[1]; }
  float s1 = 0.f, s2 = 0.f;

  #pragma unroll
  for (int half = 0; half < 2; ++half) {
    if (half == 1) __syncthreads();            // horiz(0) done before T rewrite
    // ---- vertical: 130 workers, 2 cols each via u32 reads ----
    if (t < 130) {
      int pw = (t >= 65) ? 1 : 0;
      int pc2 = t - 65 * pw;                   // u32 col-pair 0..64
      const unsigned int* E = (const unsigned int*)&S[pw][0][0] + pc2;
      const unsigned int* O = (const unsigned int*)&S[2 + pw][0][0] + pc2;
      float* Tr = &T[0][0] + pw * 132 + 2 * pc2 + 1;   // cl = 2*pc2+1, +1
      #pragma unroll
      for (int k = 0; k < 16; ++k) {
        int hl = half * 16 + k;
        int lrb = (hl + 1) >> 1;
        float v0, v1;
        if (hl & 1) {
          unsigned int e0 = E[lrb * 66],        o0 = O[lrb * 66];
          unsigned int e1 = E[(lrb + 1) * 66],  o1 = O[(lrb + 1) * 66];
          v0 = (lo16(e0) + lo16(o1)) + 3.f * (lo16(o0) + lo16(e1));
          v1 = (hi16(e0) + hi16(o1)) + 3.f * (hi16(o0) + hi16(e1));
        } else {
          unsigned int o0 = O[lrb * 66];
          unsigned int e1 = E[(lrb + 1) * 66],  o1 = O[(lrb + 1) * 66];
          unsigned int e2 = E[(lrb + 2) * 66];
          v0 = (lo16(o0) + lo16(e2)) + 3.f * (lo16(e1) + lo16(o1));
          v1 = (hi16(o0) + hi16(e2)) + 3.f * (hi16(e1) + hi16(o1));
        }
        Tr[k * 264] = v0;
        Tr[k * 264 + 1] = v1;
      }
    }
    __syncthreads();
    // ---- horizontal: thread -> (n = t&127, hh = t>>7) ----
    {
      int n = t & 127, hh = t >> 7;
      #pragma unroll
      for (int k = 0; k < 8; ++k) {
        int klocal = k * 2 + hh;               // 0..15
        const float* T0 = &T[klocal * 2][0];
        const float* T1 = &T[klocal * 2 + 1][0];
        float t0n = T0[n], t0n1 = T0[n + 1], t0n2 = T0[n + 2];
        float t1n = T1[n], t1n1 = T1[n + 1], t1n2 = T1[n + 2];
        float ve = ((t1n + t0n2) + 3.f * (t0n1 + t1n1)) * 0.0625f;
        float vo = ((t0n1 + t1n2) + 3.f * (t1n1 + t0n2)) * 0.0625f;
        if (PASS == 0) {
          s1 += ve + vo; s2 += ve * ve + vo * vo;
        } else {
          int hl = half * 16 + klocal;
          int h = 32 * g + hl;
          int par = ((klocal >> 3) & 1) * 2 + ((n >> 2) & 1);
          int lidx = half * 16 + (n >> 3);
          float msw = lsw[par][lidx], msb = lsb[par][lidx];
          float f1 = (1.f + 0.3f * msw) * rstd;
          float f0 = 0.3f * msb - mean * f1;
          float2 o = make_float2(ve * f1 + f0, vo * f1 + f0);
          *(float2*)(dout + ((size_t)bc * 256 + h) * 256 + 2 * n) = o;
        }
      }
    }
  }

  if (PASS == 0) {
    #pragma unroll
    for (int m = 32; m; m >>= 1) { s1 += __shfl_xor(s1, m, 64); s2 += __shfl_xor(s2, m, 64); }
    if (lane == 0) { rb2[wid * 2] = s1; rb2[wid * 2 + 1] = s2; }
    __syncthreads();
    if (t == 0) {
      part[((size_t)bc * 8 + g) * 2]     = rb2[0] + rb2[2] + rb2[4] + rb2[6];
      part[((size_t)bc * 8 + g) * 2 + 1] = rb2[1] + rb2[3] + rb2[5] + rb2[7];
    }
  }
}

extern "C" void kernel_launch(void* const* d_in, const int* in_sizes, int n_in,
                              void* d_out, int out_size, void* d_ws, size_t ws_size,
                              hipStream_t stream) {
  const float* x      = (const float*)d_in[0];
  const float* style  = (const float*)d_in[1];
  const float* weight = (const float*)d_in[2];
  const float* lin_w  = (const float*)d_in[3];
  const float* lin_b  = (const float*)d_in[4];
  const float* cw_w   = (const float*)d_in[5];
  const float* cw_b   = (const float*)d_in[6];
  const float* cb_w   = (const float*)d_in[7];
  const float* cb_b   = (const float*)d_in[8];
  float* out = (float*)d_out;
  char* ws = (char*)d_ws;

  short*          kbu     = (short*)(ws);                     //   294,912
  short*          kb2     = (short*)(ws + 294912);            // 1,048,576
  unsigned short* xt      = (unsigned short*)(ws + 1343488);  // 33,554,432
  unsigned short* smap_bf = (unsigned short*)(ws + 34897920); //   524,288
  float*          swp     = (float*)(ws + 35422208);          // 8,388,608
  float*          part    = (float*)(ws + 43810816);          //   131,072
  unsigned short* out1    = (unsigned short*)(ws + 43941888); // 140,574,720 (end 184.5MB)

  prep_all<<<dim3(4160), dim3(256), 0, stream>>>(
      weight, cw_w, cb_w, x, style, lin_w, lin_b, kbu, kb2, xt, smap_bf);
  modconv_kernel<<<dim3(4, 8), dim3(512), 73984, stream>>>(smap_bf, kb2, cw_b, cb_b, swp);
  convt_kernel<<<dim3(5, 65, 8), dim3(256), 0, stream>>>(xt, kbu, out1);
  blur_kernel<0><<<dim3(8, 128, 8), dim3(256), 0, stream>>>(out1, part, swp, out);
  blur_kernel<1><<<dim3(8, 128, 8), dim3(256), 0, stream>>>(out1, part, swp, out);
}

// Round 10
// 343.832 us; speedup vs baseline: 2.3390x; 1.0826x over previous
//
#include <hip/hip_runtime.h>
#include <cstdint>

// B=8, Cin=Cout=128, x 128x128 -> out 256x256.
#define SCALE_MAIN 0.029462782549439483f   // 1/sqrt(128*9)
#define LSCALE     0.044194173824159223f   // 1/sqrt(512)
#define CSCALE     0.029462782549439483f   // 1/sqrt(128*9)

typedef __attribute__((ext_vector_type(8))) short bf16x8;
typedef __attribute__((ext_vector_type(4))) float f32x4;
typedef __attribute__((ext_vector_type(2))) unsigned int u32x2;
typedef __attribute__((ext_vector_type(4))) unsigned int u32x4;

static __device__ __forceinline__ float lrelu_s2(float v) {
  return (v > 0.f ? v : 0.2f * v) * 1.4142135623730951f;
}
static __device__ __forceinline__ unsigned short f2bf(float f) {
  unsigned int u = __builtin_bit_cast(unsigned int, f);
  u += 0x7FFFu + ((u >> 16) & 1u);
  return (unsigned short)(u >> 16);
}
static __device__ __forceinline__ float lo16(unsigned int v) {
  return __builtin_bit_cast(float, v << 16);
}
static __device__ __forceinline__ float hi16(unsigned int v) {
  return __builtin_bit_cast(float, v & 0xFFFF0000u);
}
// rel even -> sc odd -> high half; rel odd -> low half. u32 index (rel+1)>>1.
#define EX(arr, rel) (((rel) & 1) ? lo16((arr)[((rel) + 1) >> 1]) : hi16((arr)[((rel) + 1) >> 1]))

// ---------------------------------------------------------------------------
// K1 prep_all (verbatim -- verified)
// ---------------------------------------------------------------------------
__global__ __launch_bounds__(256) void prep_all(
    const float* __restrict__ weight, const float* __restrict__ cw_w,
    const float* __restrict__ cb_w, const float* __restrict__ x,
    const float* __restrict__ style, const float* __restrict__ lin_w,
    const float* __restrict__ lin_b, short* __restrict__ kbu,
    short* __restrict__ kb2, unsigned short* __restrict__ xt,
    unsigned short* __restrict__ smap_bf) {
  int bid = blockIdx.x;
  int t = threadIdx.x;
  if (bid < 2048) {
    int idx = bid * 256 + t;
    int j   = idx & 7;
    int co  = (idx >> 3) & 255;
    int kc  = (idx >> 11) & 63;
    int par = idx >> 17;
    int k = kc * 8 + j;
    int t2 = k >> 7, ci = k & 127;
    int dy2 = t2 >> 1, dx2 = t2 & 1;
    int ph = par >> 1, pw = par & 1;
    const float* wsrc = (co < 128)
        ? cw_w + ((size_t)co * 128 + ci) * 9
        : cb_w + ((size_t)(co - 128) * 128 + ci) * 9;
    float acc = 0.f;
    #pragma unroll
    for (int kh = 0; kh < 3; ++kh) {
      bool okh = dy2 == 0 ? (ph == 0 ? kh == 0 : kh <= 1)
                          : (ph == 0 ? kh >= 1 : kh == 2);
      if (!okh) continue;
      #pragma unroll
      for (int kw = 0; kw < 3; ++kw) {
        bool okw = dx2 == 0 ? (pw == 0 ? kw == 0 : kw <= 1)
                            : (pw == 0 ? kw >= 1 : kw == 2);
        if (okw) acc += wsrc[kh * 3 + kw];
      }
    }
    kb2[idx] = (short)f2bf(acc * CSCALE);
  } else if (bid < 2624) {
    int idx2 = (bid - 2048) * 256 + t;       // < 147456
    int j    = idx2 & 7;
    int co   = (idx2 >> 3) & 127;
    int ksub = (idx2 >> 10) & 3;
    int s    = (idx2 >> 12) & 3;
    int tp   = idx2 >> 14;                   // tap 0..8
    int ci = s * 32 + ksub * 8 + j;
    int wr = (tp == 0 || tp == 1 || tp == 4) ? 2
           : (tp >= 6) ? 1 : 0;
    int wc = (tp == 0 || tp == 2 || tp == 6) ? 2
           : (tp == 4 || tp == 5 || tp == 8) ? 1 : 0;
    float v = weight[((size_t)(co * 128 + ci)) * 9 + wr * 3 + wc] * SCALE_MAIN;
    kbu[idx2] = (short)f2bf(v);
  } else if (bid < 3648) {
    int q = bid - 2624;
    int y = q & 127, b = q >> 7;
    __shared__ unsigned short tl[128 * 134];
    #pragma unroll 4
    for (int i = 0; i < 16; ++i) {
      int c = t + i * 256;
      int ci = c >> 5, x4 = c & 31;
      f32x4 v = *(const f32x4*)(x + (size_t)(b * 128 + ci) * 16384 + y * 128 + x4 * 4);
      unsigned int* dst = (unsigned int*)(tl + ci * 134 + x4 * 4);
      dst[0] = (unsigned int)f2bf(v.x) | ((unsigned int)f2bf(v.y) << 16);
      dst[1] = (unsigned int)f2bf(v.z) | ((unsigned int)f2bf(v.w) << 16);
    }
    __syncthreads();
    #pragma unroll 2
    for (int i = 0; i < 8; ++i) {
      int c = t + i * 256;
      int xcol = c >> 4, sub = c & 15;
      unsigned short u[8];
      #pragma unroll
      for (int j = 0; j < 8; ++j) u[j] = tl[(sub * 8 + j) * 134 + xcol];
      u32x4 o;
      o.x = (unsigned int)u[0] | ((unsigned int)u[1] << 16);
      o.y = (unsigned int)u[2] | ((unsigned int)u[3] << 16);
      o.z = (unsigned int)u[4] | ((unsigned int)u[5] << 16);
      o.w = (unsigned int)u[6] | ((unsigned int)u[7] << 16);
      *(u32x4*)(xt + ((size_t)(b * 128 + y) * 128 + xcol) * 128 + sub * 8) = o;
    }
  } else {
    int wid = t >> 6, lane = t & 63;
    int gw = (bid - 3648) * 4 + wid;
    const float4* st4 = (const float4*)style;
    float s[8][8];
    #pragma unroll
    for (int b = 0; b < 8; ++b) {
      float4 a0 = st4[b * 128 + lane * 2];
      float4 a1 = st4[b * 128 + lane * 2 + 1];
      s[b][0] = a0.x; s[b][1] = a0.y; s[b][2] = a0.z; s[b][3] = a0.w;
      s[b][4] = a1.x; s[b][5] = a1.y; s[b][6] = a1.z; s[b][7] = a1.w;
    }
    for (int rr = 0; rr < 16; ++rr) {
      int j = gw * 16 + rr;
      const float4* wp = (const float4*)(lin_w + (size_t)j * 512);
      float4 w0 = wp[lane * 2], w1 = wp[lane * 2 + 1];
      float acc[8];
      #pragma unroll
      for (int b = 0; b < 8; ++b) {
        acc[b] = w0.x * s[b][0] + w0.y * s[b][1] + w0.z * s[b][2] + w0.w * s[b][3]
               + w1.x * s[b][4] + w1.y * s[b][5] + w1.z * s[b][6] + w1.w * s[b][7];
      }
      #pragma unroll
      for (int m = 32; m; m >>= 1) {
        #pragma unroll
        for (int b = 0; b < 8; ++b) acc[b] += __shfl_xor(acc[b], m, 64);
      }
      if (lane == 0) {
        float bias = lin_b[j];
        int ci = j >> 8, sp = j & 255;
        #pragma unroll
        for (int b = 0; b < 8; ++b)
          smap_bf[(size_t)(b * 256 + sp) * 128 + ci] =
              f2bf(lrelu_s2(acc[b] * LSCALE + bias));
      }
    }
  }
}

// ---------------------------------------------------------------------------
// K2 modconv (verbatim -- verified)
// ---------------------------------------------------------------------------
__global__ __launch_bounds__(512, 2) void modconv_kernel(
    const unsigned short* __restrict__ smap_bf, const short* __restrict__ kb2,
    const float* __restrict__ cw_b, const float* __restrict__ cb_b,
    float* __restrict__ swp) {
  extern __shared__ __align__(16) char dsm[];   // 73984 B
  int par = blockIdx.x, b = blockIdx.y;
  int ph = par >> 1, pw = par & 1;
  int t = threadIdx.x, lane = t & 63, w = t >> 6;
  int q = w >> 1, ch = w & 1;
  int m15 = lane & 15, ksub = lane >> 4;

  for (int c = t; c < 4624; c += 512) {
    int s = c >> 4, cch = c & 15;
    int rr = s / 17, cc = s - rr * 17;
    int gr = rr - 1 + ph, gc = cc - 1 + pw;
    u32x4 v = {0u, 0u, 0u, 0u};
    if ((unsigned)gr < 16u && (unsigned)gc < 16u)
      v = *(const u32x4*)(smap_bf + ((size_t)(b * 256 + gr * 16 + gc) * 128 + cch * 8));
    int phys = (cch + s) & 15;
    *(u32x4*)(dsm + s * 256 + phys * 16) = v;
  }
  __syncthreads();

  const bf16x8* kbv = (const bf16x8*)kb2;
  f32x4 acc[4][8];
  #pragma unroll
  for (int i = 0; i < 4; ++i)
  #pragma unroll
  for (int j = 0; j < 8; ++j) acc[i][j] = (f32x4){0.f, 0.f, 0.f, 0.f};

  for (int s = 0; s < 16; ++s) {
    int t2 = s >> 2, dy2 = t2 >> 1, dx2 = t2 & 1;
    int cch = (s & 3) * 4 + ksub;
    bf16x8 av[4];
    #pragma unroll
    for (int mf = 0; mf < 4; ++mf) {
      int i = q * 4 + mf;
      int ssp = (i + dy2) * 17 + (m15 + dx2);
      int phys = (cch + ssp) & 15;
      av[mf] = *(const bf16x8*)(dsm + ssp * 256 + phys * 16);
    }
    #pragma unroll
    for (int nf = 0; nf < 8; ++nf) {
      bf16x8 bv = kbv[(size_t)((par * 64 + s * 4 + ksub) * 256 + ch * 128 + nf * 16 + m15)];
      #pragma unroll
      for (int mf = 0; mf < 4; ++mf)
        acc[mf][nf] = __builtin_amdgcn_mfma_f32_16x16x32_bf16(av[mf], bv, acc[mf][nf], 0, 0, 0);
    }
  }

  int jbase = ksub * 4;
  #pragma unroll
  for (int nf = 0; nf < 8; ++nf) {
    int co = ch * 128 + nf * 16 + m15;
    float bias = (co < 128) ? cw_b[co] : cb_b[co - 128];
    #pragma unroll
    for (int mf = 0; mf < 4; ++mf) {
      int i = q * 4 + mf;
      #pragma unroll
      for (int r = 0; r < 4; ++r) {
        int px = i * 16 + jbase + r;
        swp[((size_t)(b * 256 + co) * 4 + par) * 256 + px] = acc[mf][nf][r] + bias;
      }
    }
  }
}

// ---------------------------------------------------------------------------
// K3 convt v2 (verbatim -- verified): unfused transposed conv -> 4 parity
// planes bf16, out1[b][pl][co][130][132].
// ---------------------------------------------------------------------------
__global__ __launch_bounds__(256, 2) void convt_kernel(
    const unsigned short* __restrict__ xt, const short* __restrict__ kbu,
    unsigned short* __restrict__ out1) {
  __shared__ __align__(16) char smem[26112];   // A-tile 102*256; reused as eps
  int cg = blockIdx.x, rp = blockIdx.y, b = blockIdx.z;
  int t = threadIdx.x, lane = t & 63, w = t >> 6;
  int m15 = lane & 15, ksub = lane >> 4;
  int pl = (w + cg + rp) & 3;                  // wave's plane, SIMD-balanced
  int tstart = (pl == 0) ? 0 : 2 + 2 * pl;     // {0,4,6,8}
  int nst = 16 >> ((pl + 1) >> 1);             // {16,8,8,4}

  const char* xtc = (const char*)xt;
  for (int c = t; c < 1632; c += 256) {
    int spos = c >> 4, sub = c & 15;
    int lr = spos / 34, lc = spos - lr * 34;
    int y = 2 * rp - 1 + lr, xg = 32 * cg - 1 + lc;
    f32x4 v = {0.f, 0.f, 0.f, 0.f};
    if ((unsigned)y < 128u && (unsigned)xg < 128u)
      v = *(const f32x4*)(xtc + ((size_t)((b * 128 + y) * 128 + xg)) * 256 + sub * 16);
    int phys = (sub & 8) | ((sub ^ spos) & 7);
    *(f32x4*)(smem + spos * 256 + phys * 16) = v;
  }
  __syncthreads();

  const bf16x8* kbv = (const bf16x8*)kbu;
  f32x4 acc[4][8];
  #pragma unroll
  for (int i = 0; i < 4; ++i)
  #pragma unroll
  for (int j = 0; j < 8; ++j) acc[i][j] = (f32x4){0.f, 0.f, 0.f, 0.f};

  auto LD = [&](int s, bf16x8* av, bf16x8* bv) {
    int tap = tstart + (s >> 2);
    int du = -((0x13 >> tap) & 1);
    int dv = -((0x45 >> tap) & 1);
    int cc = s & 3;
    int c = cc * 4 + ksub;
    #pragma unroll
    for (int mf = 0; mf < 4; ++mf) {
      int spos = ((mf >> 1) + du + 1) * 34 + (mf & 1) * 16 + m15 + dv + 1;
      int phys = (c & 8) | ((c ^ spos) & 7);
      av[mf] = *(const bf16x8*)(smem + spos * 256 + phys * 16);
    }
    int bb = tap * 2048 + cc * 512 + ksub * 128 + m15;
    #pragma unroll
    for (int nf = 0; nf < 8; ++nf) bv[nf] = kbv[bb + nf * 16];
  };
  auto MM = [&](bf16x8* av, bf16x8* bv) {
    __builtin_amdgcn_s_setprio(1);
    #pragma unroll
    for (int nf = 0; nf < 8; ++nf)
    #pragma unroll
    for (int mf = 0; mf < 4; ++mf)
      acc[mf][nf] = __builtin_amdgcn_mfma_f32_16x16x32_bf16(av[mf], bv[nf], acc[mf][nf], 0, 0, 0);
    __builtin_amdgcn_s_setprio(0);
  };

  bf16x8 aA[4], bA[8], aB[4], bB[8];
  LD(0, aA, bA);
  for (int s = 0; s + 2 <= nst; s += 2) {
    LD(s + 1, aB, bB);
    MM(aA, bA);
    if (s + 2 < nst) LD(s + 2, aA, bA);
    MM(aB, bB);
  }

  __syncthreads();
  float* eps = (float*)smem;                   // [pl 4][px 64][17]
  int t63 = t & 63, wpl = t >> 6;
  #pragma unroll
  for (int nf = 0; nf < 8; ++nf) {
    #pragma unroll
    for (int mf = 0; mf < 4; ++mf)
    #pragma unroll
    for (int r = 0; r < 4; ++r)
      eps[(pl * 64 + mf * 16 + ksub * 4 + r) * 17 + m15] = acc[mf][nf][r];
    __syncthreads();
    #pragma unroll
    for (int k = 0; k < 4; ++k) {
      int slot = k * 64 + t63;                 // [co16:4][pr:1][ch:3]
      int co16 = slot >> 4, pr = (slot >> 3) & 1, ch = slot & 7;
      float v0 = eps[(wpl * 64 + pr * 32 + ch * 4 + 0) * 17 + co16];
      float v1 = eps[(wpl * 64 + pr * 32 + ch * 4 + 1) * 17 + co16];
      float v2 = eps[(wpl * 64 + pr * 32 + ch * 4 + 2) * 17 + co16];
      float v3 = eps[(wpl * 64 + pr * 32 + ch * 4 + 3) * 17 + co16];
      u32x2 o;
      o.x = (unsigned int)f2bf(v0) | ((unsigned int)f2bf(v1) << 16);
      o.y = (unsigned int)f2bf(v2) | ((unsigned int)f2bf(v3) << 16);
      int co = nf * 16 + co16;
      int r = 2 * rp + pr;
      size_t ob = (((size_t)(b * 4 + wpl) * 128 + co) * 130 + r) * 132
                + 32 * cg + ch * 4;
      if (cg < 4 || ch == 0) *(u32x2*)(out1 + ob) = o;
    }
    __syncthreads();
  }
}

// ---------------------------------------------------------------------------
// K4/K5 blur v5: single-stage 2D stencil. Thread = 4 out rows x 8 out cols,
// computed from 56 u32 LDS reads held in registers (E rows 3, O rows 4,
// 4 u32 per row per col-parity). One barrier; all 256 threads active;
// division-free staging. S[lr][pl][144], sc = plane col + 8 (sc 6..7 = zeros
// for cols -2..-1). Block (g,co,b): out rows [32g,32g+32) x 256 cols.
// ---------------------------------------------------------------------------
template <int PASS>
__global__ __launch_bounds__(256) void blur_kernel(
    const unsigned short* __restrict__ out1, float* __restrict__ part,
    const float* __restrict__ swp, float* __restrict__ dout) {
  __shared__ unsigned short S[18][4][144];     // 20736 B
  __shared__ float lsw[4][32], lsb[4][32];
  __shared__ float msh[2];
  __shared__ float rb2[8];
  int g = blockIdx.x, co = blockIdx.y, b = blockIdx.z;
  int t = threadIdx.x, lane = t & 63, wid = t >> 6;
  int bc = b * 128 + co;

  if (PASS == 1) {
    if (t == 0) {
      float a1 = 0.f, a2 = 0.f;
      #pragma unroll
      for (int i = 0; i < 8; ++i) {
        a1 += part[((size_t)bc * 8 + i) * 2];
        a2 += part[((size_t)bc * 8 + i) * 2 + 1];
      }
      float mean = a1 * (1.f / 65536.f);
      float var = a2 * (1.f / 65536.f) - mean * mean;
      msh[0] = mean; msh[1] = rsqrtf(var + 1e-5f);
    }
    {   // swp cache: [which][par][hrow*16+wcol]
      int which = t >> 7;
      int par = (t >> 5) & 3;
      int idx = t & 31;
      int hrow = idx >> 4, wcol = idx & 15;
      int px2 = (2 * g + hrow) * 16 + wcol;
      float v = swp[((size_t)(b * 256 + which * 128 + co) * 4 + par) * 256 + px2];
      if (which == 0) lsw[par][idx] = v; else lsb[par][idx] = v;
    }
  }

  // ---- stage S: rows lr 0..17 (plane row 16g-1+lr), 4 planes, cols 0..131 ----
  int rbase = 16 * g - 1;
  for (int i = t; i < 1152; i += 256) {        // main: 16B chunks, cols 0..127
    int rid = i >> 4, ch = i & 15;
    int lr = rid >> 2, pl = rid & 3;
    int r = rbase + lr;
    u32x2 v0 = {0u, 0u}, v1 = {0u, 0u};
    if (r >= 0) {
      const unsigned short* src =
          out1 + ((size_t)((b * 4 + pl) * 128 + co) * 130 + r) * 132 + ch * 8;
      v0 = *(const u32x2*)(src);
      v1 = *(const u32x2*)(src + 4);
    }
    *(u32x2*)(&S[lr][pl][8 + ch * 8]) = v0;
    *(u32x2*)(&S[lr][pl][12 + ch * 8]) = v1;
  }
  if (t < 72) {                                // tail: cols 128..131
    int lr = t >> 2, pl = t & 3;
    int r = rbase + lr;
    u32x2 v = {0u, 0u};
    if (r >= 0)
      v = *(const u32x2*)(out1 + ((size_t)((b * 4 + pl) * 128 + co) * 130 + r) * 132 + 128);
    *(u32x2*)(&S[lr][pl][136]) = v;
  }
  if (t >= 128 && t < 200) {                   // zeros: cols -2,-1 (sc 6,7)
    int q = t - 128;
    *(unsigned int*)(&S[q >> 2][q & 3][6]) = 0u;
  }
  __syncthreads();

  float mean = 0.f, rstd = 0.f;
  if (PASS == 1) { mean = msh[0]; rstd = msh[1]; }

  // ---- per-thread register window: E pl{0,1} rows sr+1..sr+3, O pl{2,3} sr..sr+3 ----
  int rg = t >> 5, cg = t & 31;
  int sr = 2 * rg;
  unsigned int Eu[2][3][4], Ou[2][4][4];
  #pragma unroll
  for (int cp = 0; cp < 2; ++cp) {
    #pragma unroll
    for (int rr = 0; rr < 3; ++rr) {
      const unsigned int* p = (const unsigned int*)&S[sr + 1 + rr][cp][0];
      #pragma unroll
      for (int j = 0; j < 4; ++j) Eu[cp][rr][j] = p[2 * cg + 3 + j];
    }
    #pragma unroll
    for (int rr = 0; rr < 4; ++rr) {
      const unsigned int* p = (const unsigned int*)&S[sr + rr][2 + cp][0];
      #pragma unroll
      for (int j = 0; j < 4; ++j) Ou[cp][rr][j] = p[2 * cg + 3 + j];
    }
  }

  float s1 = 0.f, s2 = 0.f;
  #pragma unroll
  for (int k = 0; k < 4; ++k) {
    const int a = (k + 1) >> 1;                // O row base (k:0,1,1,2)
    float Tc[2][6];
    #pragma unroll
    for (int cp = 0; cp < 2; ++cp)
    #pragma unroll
    for (int rel = 0; rel < 6; ++rel) {
      float v;
      if ((k & 1) == 0)
        v = EX(Ou[cp][a], rel) + 3.f * EX(Eu[cp][a], rel)
          + 3.f * EX(Ou[cp][a + 1], rel) + EX(Eu[cp][a + 1], rel);
      else
        v = EX(Eu[cp][a - 1], rel) + 3.f * EX(Ou[cp][a], rel)
          + 3.f * EX(Eu[cp][a], rel) + EX(Ou[cp][a + 1], rel);
      Tc[cp][rel] = v;
    }
    float o8[8];
    #pragma unroll
    for (int i = 0; i < 4; ++i) {
      float ve = ((Tc[1][i] + Tc[0][i + 2]) + 3.f * (Tc[0][i + 1] + Tc[1][i + 1])) * 0.0625f;
      float vo = ((Tc[0][i + 1] + Tc[1][i + 2]) + 3.f * (Tc[1][i + 1] + Tc[0][i + 2])) * 0.0625f;
      if (PASS == 0) {
        s1 += ve + vo; s2 += ve * ve + vo * vo;
      } else {
        o8[2 * i] = ve; o8[2 * i + 1] = vo;
      }
    }
    if (PASS == 1) {
      int hl = 4 * rg + k;
      int h = 32 * g + hl;
      int par = ((hl >> 3) & 1) * 2 + (cg & 1);
      int lidx = ((hl >> 4) & 1) * 16 + (cg >> 1);
      float f1 = (1.f + 0.3f * lsw[par][lidx]) * rstd;
      float f0 = 0.3f * lsb[par][lidx] - mean * f1;
      f32x4 oA = {o8[0] * f1 + f0, o8[1] * f1 + f0, o8[2] * f1 + f0, o8[3] * f1 + f0};
      f32x4 oB = {o8[4] * f1 + f0, o8[5] * f1 + f0, o8[6] * f1 + f0, o8[7] * f1 + f0};
      float* op = dout + ((size_t)bc * 256 + h) * 256 + 8 * cg;
      *(f32x4*)(op) = oA;
      *(f32x4*)(op + 4) = oB;
    }
  }

  if (PASS == 0) {
    #pragma unroll
    for (int m = 32; m; m >>= 1) { s1 += __shfl_xor(s1, m, 64); s2 += __shfl_xor(s2, m, 64); }
    if (lane == 0) { rb2[wid * 2] = s1; rb2[wid * 2 + 1] = s2; }
    __syncthreads();
    if (t == 0) {
      part[((size_t)bc * 8 + g) * 2]     = rb2[0] + rb2[2] + rb2[4] + rb2[6];
      part[((size_t)bc * 8 + g) * 2 + 1] = rb2[1] + rb2[3] + rb2[5] + rb2[7];
    }
  }
}

extern "C" void kernel_launch(void* const* d_in, const int* in_sizes, int n_in,
                              void* d_out, int out_size, void* d_ws, size_t ws_size,
                              hipStream_t stream) {
  const float* x      = (const float*)d_in[0];
  const float* style  = (const float*)d_in[1];
  const float* weight = (const float*)d_in[2];
  const float* lin_w  = (const float*)d_in[3];
  const float* lin_b  = (const float*)d_in[4];
  const float* cw_w   = (const float*)d_in[5];
  const float* cw_b   = (const float*)d_in[6];
  const float* cb_w   = (const float*)d_in[7];
  const float* cb_b   = (const float*)d_in[8];
  float* out = (float*)d_out;
  char* ws = (char*)d_ws;

  short*          kbu     = (short*)(ws);                     //   294,912
  short*          kb2     = (short*)(ws + 294912);            // 1,048,576
  unsigned short* xt      = (unsigned short*)(ws + 1343488);  // 33,554,432
  unsigned short* smap_bf = (unsigned short*)(ws + 34897920); //   524,288
  float*          swp     = (float*)(ws + 35422208);          // 8,388,608
  float*          part    = (float*)(ws + 43810816);          //   131,072
  unsigned short* out1    = (unsigned short*)(ws + 43941888); // 140,574,720 (end 184.5MB)

  prep_all<<<dim3(4160), dim3(256), 0, stream>>>(
      weight, cw_w, cb_w, x, style, lin_w, lin_b, kbu, kb2, xt, smap_bf);
  modconv_kernel<<<dim3(4, 8), dim3(512), 73984, stream>>>(smap_bf, kb2, cw_b, cb_b, swp);
  convt_kernel<<<dim3(5, 65, 8), dim3(256), 0, stream>>>(xt, kbu, out1);
  blur_kernel<0><<<dim3(8, 128, 8), dim3(256), 0, stream>>>(out1, part, swp, out);
  blur_kernel<1><<<dim3(8, 128, 8), dim3(256), 0, stream>>>(out1, part, swp, out);
}